// Round 14
// baseline (235.686 us; speedup 1.0000x reference)
//
#include <hip/hip_runtime.h>

typedef float  f32x4  __attribute__((ext_vector_type(4)));
typedef float  f32x16 __attribute__((ext_vector_type(16)));
typedef __bf16 bf16x2 __attribute__((ext_vector_type(2)));
typedef __bf16 bf16x4 __attribute__((ext_vector_type(4)));
typedef __bf16 bf16x8 __attribute__((ext_vector_type(8)));
typedef unsigned int u32;
typedef u32 u32x4 __attribute__((ext_vector_type(4)));

#define MFMA16(a, b, c) __builtin_amdgcn_mfma_f32_16x16x32_bf16((a), (b), (c), 0, 0, 0)
#define MFMA32(a, b, c) __builtin_amdgcn_mfma_f32_32x32x16_bf16((a), (b), (c), 0, 0, 0)

constexpr int EMB  = 1024;
constexpr int NSEQ = 2048;
constexpr int NB   = 4;
constexpr int NH   = 16;
constexpr int DH   = 64;
constexpr size_t HSTRIDE = (size_t)NSEQ * DH;        // elements per head (Q/K)
constexpr size_t MAT     = (size_t)NB * NSEQ * EMB;  // 8388608
constexpr size_t WSZ     = (size_t)EMB * EMB;        // 1048576
constexpr int    BSEQ    = NB * NSEQ;                // 8192 (V^T row length)
constexpr float  QSCALE  = 0.18033688011112042f;     // 0.125 * log2(e)

__device__ __forceinline__ __bf16 f2bf(float f) { return (__bf16)f; }

__device__ __forceinline__ u32 pkbf(float a, float b) {
  bf16x2 t = {(__bf16)a, (__bf16)b};
  return __builtin_bit_cast(u32, t);
}

// XOR swizzle (involution) for 128B-row tiles: rows (bits 7-9) into 16B-slot bits (4-6).
__device__ __forceinline__ int swz(int a) { return a ^ (((a >> 7) & 7) << 4); }

// async global->LDS, 16B per lane; LDS dest = wave-uniform base + lane*16.
__device__ __forceinline__ void gll16(const void* g, void* l) {
  __builtin_amdgcn_global_load_lds((const __attribute__((address_space(1))) unsigned*)g,
                                   (__attribute__((address_space(3))) unsigned*)l, 16, 0, 0);
}

#define SCHEDBAR() __builtin_amdgcn_sched_barrier(0)
#define RAWBAR()   __builtin_amdgcn_s_barrier()

// ================= conversion pre-pass (single launch) =================
__global__ __launch_bounds__(256) void cvt_all(const float* __restrict__ x,
                                               const float* __restrict__ w0,
                                               const float* __restrict__ w1,
                                               const float* __restrict__ w2,
                                               const float* __restrict__ w3,
                                               __bf16* __restrict__ Xbf,
                                               __bf16* __restrict__ Wbf) {
  const int xblocks = (int)(MAT / 4 / 256);
  const int wslice  = (int)(WSZ / 4 / 256);
  const float* src;
  __bf16* dst;
  size_t idx;
  if (blockIdx.x < (unsigned)xblocks) {
    src = x; dst = Xbf;
    idx = (size_t)blockIdx.x * 256 + threadIdx.x;
  } else {
    int j = blockIdx.x - xblocks;
    int z = j / wslice, r = j % wslice;
    const float* srcs[4] = {w0, w1, w2, w3};
    src = srcs[z];
    dst = Wbf + (size_t)z * WSZ;
    idx = (size_t)r * 256 + threadIdx.x;
  }
  f32x4 v = *reinterpret_cast<const f32x4*>(src + idx * 4);
  bf16x4 o = {f2bf(v[0]), f2bf(v[1]), f2bf(v[2]), f2bf(v[3])};
  *reinterpret_cast<bf16x4*>(dst + idx * 4) = o;
}

// ================= 256x256 pipelined GEMM core (counted vmcnt, no drain) =================
// BK=64, 8 waves (2M x 4N), per-wave output 128x64 -> acc[8][4] (128 VGPR).
// LDS: A,B double-buffered 32KB tiles (128KB). Per K-step: 8 gll in fixed order
// [B0,B1,B2,B3,A0,A2,A1,A3]; each tile's chunks land one full K-step before use.
// Sync per K-step: vmcnt(2)+barrier at flip (oldest 6 chunks = B*+A0,A2 ready;
// A1,A3 may fly), 32 MFMA on M-half0, vmcnt(8)+barrier (A1,A3 ready; next tile's
// 8 in flight), 32 MFMA on M-half1. vmcnt never drains to 0 in the loop.
__device__ __forceinline__ void gemm256(const char* Ac, const char* Wc,
                                        int m0, int n0,
                                        __bf16 (*sA)[16384], __bf16 (*sB)[16384],
                                        f32x4 (&acc)[8][4]) {
  const int tid = threadIdx.x;
  const int lane = tid & 63, w = tid >> 6;
  const int wm = w >> 2, wn = w & 3;
  const int l15 = lane & 15, g = lane >> 4;
  const int srow = tid >> 3;                       // 64 rows per 8KB chunk
  const int scol = ((tid & 7) ^ (srow & 7)) * 16;  // pre-swizzled source col byte

  int offA[2][4][2], offB[4][2];
#pragma unroll
  for (int mh = 0; mh < 2; ++mh)
#pragma unroll
    for (int i = 0; i < 4; ++i)
#pragma unroll
      for (int ks = 0; ks < 2; ++ks) {
        int r = wm * 128 + mh * 64 + i * 16 + l15;
        offA[mh][i][ks] = (r * 128 + ((ks * 64 + g * 16) ^ ((l15 & 7) << 4))) >> 1;
      }
#pragma unroll
  for (int i = 0; i < 4; ++i)
#pragma unroll
    for (int ks = 0; ks < 2; ++ks) {
      int r = wn * 64 + i * 16 + l15;
      offB[i][ks] = (r * 128 + ((ks * 64 + g * 16) ^ ((l15 & 7) << 4))) >> 1;
    }

  auto stage = [&](int tile, int bf) {
    const size_t cb = (size_t)tile * 128 + scol;   // byte col offset (k0*2 + scol)
    // B chunks 0..3 first (needed by every phase), then A 0,2 (half0), A 1,3 (half1)
#pragma unroll
    for (int c = 0; c < 4; ++c)
      gll16(Wc + (size_t)(n0 + c * 64 + srow) * 2048 + cb, &sB[bf][c * 4096 + tid * 8]);
    gll16(Ac + (size_t)(m0 + 0 * 64 + srow) * 2048 + cb, &sA[bf][0 * 4096 + tid * 8]);
    gll16(Ac + (size_t)(m0 + 2 * 64 + srow) * 2048 + cb, &sA[bf][2 * 4096 + tid * 8]);
    gll16(Ac + (size_t)(m0 + 1 * 64 + srow) * 2048 + cb, &sA[bf][1 * 4096 + tid * 8]);
    gll16(Ac + (size_t)(m0 + 3 * 64 + srow) * 2048 + cb, &sA[bf][3 * 4096 + tid * 8]);
  };

  auto compute_half = [&](int p, int mh) {
#pragma unroll
    for (int ks = 0; ks < 2; ++ks) {
      bf16x8 af[4], bfv[4];
#pragma unroll
      for (int i = 0; i < 4; ++i)
        af[i] = *reinterpret_cast<const bf16x8*>(&sA[p][offA[mh][i][ks]]);
#pragma unroll
      for (int i = 0; i < 4; ++i)
        bfv[i] = *reinterpret_cast<const bf16x8*>(&sB[p][offB[i][ks]]);
      __builtin_amdgcn_s_setprio(1);
#pragma unroll
      for (int mi = 0; mi < 4; ++mi)
#pragma unroll
        for (int ni = 0; ni < 4; ++ni)
          acc[mh * 4 + mi][ni] = MFMA16(af[mi], bfv[ni], acc[mh * 4 + mi][ni]);
      __builtin_amdgcn_s_setprio(0);
    }
  };

  stage(0, 0);

#pragma unroll 1
  for (int t = 0; t < 16; ++t) {
    const int p = t & 1;
    asm volatile("s_waitcnt vmcnt(2)" ::: "memory");   // tile t: B*,A0,A2 landed
    SCHEDBAR();
    RAWBAR();                                          // cross-wave handoff
    SCHEDBAR();
    stage((t + 1) & 15, p ^ 1);                        // t=15 restage is harmless
    compute_half(p, 0);
    asm volatile("s_waitcnt vmcnt(8)" ::: "memory");   // tile t: A1,A3 landed
    SCHEDBAR();
    RAWBAR();
    SCHEDBAR();
    compute_half(p, 1);
  }
}

// ================= fused QKV projections, 256x256 pipelined =================
// 384 blocks: logical -> (m in [0,32), n in [0,4), z in {Q,K,V}); XCD-swizzled
// so 12 consecutive logicals (same m, 4n x 3z) share an XCD L2 A-panel.
__global__ __launch_bounds__(512) void qkv256(const __bf16* __restrict__ Xbf,
                                              const __bf16* __restrict__ Wbf,
                                              const float* __restrict__ bq,
                                              const float* __restrict__ bk,
                                              const float* __restrict__ bv,
                                              __bf16* __restrict__ Qw,
                                              __bf16* __restrict__ Kw,
                                              __bf16* __restrict__ Vtw) {
  __shared__ __align__(16) __bf16 sA[2][16384];
  __shared__ __align__(16) __bf16 sB[2][16384];

  int flat = blockIdx.x;                         // 384
  int logical = (flat & 7) * 48 + (flat >> 3);   // bijective (384 % 8 == 0)
  const int m = logical / 12, r = logical % 12;
  const int n = r / 3, z = r % 3;
  const int m0 = m * 256, n0 = n * 256;

  f32x4 acc[8][4];
#pragma unroll
  for (int i = 0; i < 8; ++i)
#pragma unroll
    for (int j = 0; j < 4; ++j) acc[i][j] = f32x4{0.f, 0.f, 0.f, 0.f};

  gemm256((const char*)Xbf, (const char*)(Wbf + (size_t)z * WSZ), m0, n0, sA, sB, acc);

  const int tid = threadIdx.x;
  const int lane = tid & 63, w = tid >> 6;
  const int wm = w >> 2, wn = w & 3;
  const int l15 = lane & 15, g = lane >> 4;
  const float* bias = (z == 0) ? bq : (z == 1) ? bk : bv;

#pragma unroll
  for (int mi = 0; mi < 8; ++mi)
#pragma unroll
    for (int ni = 0; ni < 4; ++ni) {
      int cg = n0 + wn * 64 + ni * 16 + l15;
      int hh = cg >> 6, d = cg & (DH - 1);
      float bc = bias[cg];
      if (z == 2) {
        // V: C^T layout Vt[cg][rg], 4 consecutive rg -> one 8B store
        int rg0 = m0 + wm * 128 + mi * 16 + g * 4;
        bf16x4 pv = {f2bf(acc[mi][ni][0] + bc), f2bf(acc[mi][ni][1] + bc),
                     f2bf(acc[mi][ni][2] + bc), f2bf(acc[mi][ni][3] + bc)};
        *reinterpret_cast<bf16x4*>(Vtw + (size_t)cg * BSEQ + rg0) = pv;
      } else {
#pragma unroll
        for (int j = 0; j < 4; ++j) {
          int rg = m0 + wm * 128 + mi * 16 + g * 4 + j;
          int bb = rg >> 11, rr = rg & (NSEQ - 1);
          size_t idx = (((size_t)(bb * NH + hh)) * NSEQ + rr) * DH + d;
          if (z == 0) Qw[idx] = f2bf((acc[mi][ni][j] + bc) * QSCALE);
          else        Kw[idx] = f2bf(acc[mi][ni][j] + bc);
        }
      }
    }
}

// ================= output projection, 256x256 pipelined =================
__global__ __launch_bounds__(512) void oproj256(const __bf16* __restrict__ Abf,
                                                const __bf16* __restrict__ W,
                                                const float* __restrict__ bias,
                                                float* __restrict__ outp) {
  __shared__ __align__(16) __bf16 sA[2][16384];
  __shared__ __align__(16) __bf16 sB[2][16384];

  int flat = blockIdx.x;                         // 128
  int logical = (flat & 7) * 16 + (flat >> 3);
  const int m0 = (logical >> 2) * 256, n0 = (logical & 3) * 256;

  f32x4 acc[8][4];
#pragma unroll
  for (int i = 0; i < 8; ++i)
#pragma unroll
    for (int j = 0; j < 4; ++j) acc[i][j] = f32x4{0.f, 0.f, 0.f, 0.f};

  gemm256((const char*)Abf, (const char*)W, m0, n0, sA, sB, acc);

  const int tid = threadIdx.x;
  const int lane = tid & 63, w = tid >> 6;
  const int wm = w >> 2, wn = w & 3;
  const int l15 = lane & 15, g = lane >> 4;

#pragma unroll
  for (int mi = 0; mi < 8; ++mi)
#pragma unroll
    for (int ni = 0; ni < 4; ++ni) {
      int cg = n0 + wn * 64 + ni * 16 + l15;
      float bc = bias[cg];
#pragma unroll
      for (int j = 0; j < 4; ++j) {
        int rg = m0 + wm * 128 + mi * 16 + g * 4 + j;
        outp[(size_t)rg * EMB + cg] = acc[mi][ni][j] + bc;
      }
    }
}

// ================= Flash attention (r13 proven, unchanged) =================
__global__ __launch_bounds__(512) void flash_kernel(const __bf16* __restrict__ Qb,
                                                    const __bf16* __restrict__ Kb,
                                                    const __bf16* __restrict__ Vtb,
                                                    float* __restrict__ attnw,
                                                    __bf16* __restrict__ attnw_bf) {
  __shared__ __align__(16) __bf16 lds[2][16384];  // [buf][ K:8192 | V:8192 ] elements
  const int t = threadIdx.x;
  const int lane = t & 63, w = t >> 6;            // w in [0,8)
  const int l31 = lane & 31, hi = lane >> 5;

  int flat = blockIdx.x + 8 * (blockIdx.y + NH * blockIdx.z);
  int logical = (flat & 7) * 64 + (flat >> 3);
  const int qt = logical & 7, h = (logical >> 3) & 15, b = logical >> 7;

  const size_t hoff = ((size_t)(b * NH + h)) * HSTRIDE;
  const __bf16* Qh = Qb + hoff;                  // [2048][64]
  const char* Kc = (const char*)(Kb + hoff);     // [2048][64]  row = 128 B
  const char* Vc = (const char*)(Vtb + (size_t)(h * DH) * BSEQ + (size_t)b * NSEQ);
  const int q0 = qt * 256 + w * 32;              // this wave's 32 q-rows

  bf16x8 qf[4];
#pragma unroll
  for (int ds = 0; ds < 4; ++ds)
    qf[ds] = *reinterpret_cast<const bf16x8*>(Qh + (size_t)(q0 + l31) * DH + ds * 16 + hi * 8);

  int koff[2][4], voff[4][2];
#pragma unroll
  for (int kt32 = 0; kt32 < 2; ++kt32)
#pragma unroll
    for (int ds = 0; ds < 4; ++ds)
      koff[kt32][ds] = swz((kt32 * 32 + l31) * 128 + ds * 32 + hi * 16) >> 1;
#pragma unroll
  for (int c = 0; c < 4; ++c)
#pragma unroll
    for (int db = 0; db < 2; ++db)
      voff[c][db] = swz((db * 32 + l31) * 128 + c * 32 + hi * 16) >> 1;

  // stage a 128-kv tile (K 16KB + V 16KB); V row stride = BSEQ*2 = 16KB
  auto stage = [&](int bf, int kt) {
#pragma unroll
    for (int hh = 0; hh < 2; ++hh) {
      int L = w * 1024 + lane * 16;
      int s = swz(L);
      gll16(Kc + (size_t)(kt + hh * 64) * 128 + s, &lds[bf][hh * 4096 + w * 512]);
      int d = s >> 7, rem = s & 127;
      gll16(Vc + (size_t)d * (BSEQ * 2) + (kt + hh * 64) * 2 + rem,
            &lds[bf][8192 + hh * 4096 + w * 512]);
    }
  };

  f32x16 o0{}, o1{}, osum{};
  const f32x16 kZero{};                 // hoisted zero C operand
  bf16x8 vones;
#pragma unroll
  for (int i = 0; i < 8; ++i) vones[i] = (__bf16)1.0f;

  stage(0, 0);
  __syncthreads();

#pragma unroll 1
  for (int it = 0; it < NSEQ / 128; ++it) {
    const int cur = it & 1;
    if (it + 1 < NSEQ / 128) stage(cur ^ 1, (it + 1) * 128);

#pragma unroll
    for (int sub = 0; sub < 2; ++sub) {
      const __bf16* Kl = lds[cur] + sub * 4096;
      const __bf16* Vl = lds[cur] + 8192 + sub * 4096;

      bf16x8 kf[2][4];
#pragma unroll
      for (int kt32 = 0; kt32 < 2; ++kt32)
#pragma unroll
        for (int ds = 0; ds < 4; ++ds)
          kf[kt32][ds] = *reinterpret_cast<const bf16x8*>(Kl + koff[kt32][ds]);

      f32x16 s0, s1;
      __builtin_amdgcn_s_setprio(1);
      s0 = MFMA32(kf[0][0], qf[0], kZero);
      s1 = MFMA32(kf[1][0], qf[0], kZero);
#pragma unroll
      for (int ds = 1; ds < 4; ++ds) s0 = MFMA32(kf[0][ds], qf[ds], s0);
#pragma unroll
      for (int ds = 1; ds < 4; ++ds) s1 = MFMA32(kf[1][ds], qf[ds], s1);
      __builtin_amdgcn_s_setprio(0);

      bf16x8 vf[4][2];
#pragma unroll
      for (int c = 0; c < 4; ++c)
#pragma unroll
        for (int db = 0; db < 2; ++db)
          vf[c][db] = *reinterpret_cast<const bf16x8*>(Vl + voff[c][db]);

#pragma unroll
      for (int r = 0; r < 16; ++r) s0[r] = __builtin_exp2f(s0[r]);
#pragma unroll
      for (int r = 0; r < 16; ++r) s1[r] = __builtin_exp2f(s1[r]);

      u32 pk0[8], pk1[8];
#pragma unroll
      for (int j = 0; j < 8; ++j) pk0[j] = pkbf(s0[2 * j], s0[2 * j + 1]);
#pragma unroll
      for (int j = 0; j < 8; ++j) pk1[j] = pkbf(s1[2 * j], s1[2 * j + 1]);

      auto pv_step = [&](u32& a0, u32& a1, u32& a2, u32& a3, int c) {
        asm("v_permlane32_swap_b32 %0, %1" : "+v"(a0), "+v"(a2));
        asm("v_permlane32_swap_b32 %0, %1" : "+v"(a1), "+v"(a3));
        u32x4 wv = {a0, a1, a2, a3};
        bf16x8 pa = __builtin_bit_cast(bf16x8, wv);
        o0 = MFMA32(pa, vf[c][0], o0);
        o1 = MFMA32(pa, vf[c][1], o1);
        osum = MFMA32(pa, vones, osum);
      };
      __builtin_amdgcn_s_setprio(1);
      pv_step(pk0[0], pk0[1], pk0[2], pk0[3], 0);
      pv_step(pk0[4], pk0[5], pk0[6], pk0[7], 1);
      pv_step(pk1[0], pk1[1], pk1[2], pk1[3], 2);
      pv_step(pk1[4], pk1[5], pk1[6], pk1[7], 3);
      __builtin_amdgcn_s_setprio(0);
    }

    __syncthreads();   // drains staging vmcnt + lgkm; safe buffer flip
  }

#pragma unroll
  for (int r = 0; r < 16; ++r) {
    int qq = (r & 3) + 8 * (r >> 2) + 4 * hi;
    float invq = 1.0f / osum[r];
    int row = q0 + qq;
    float v0 = o0[r] * invq, v1 = o1[r] * invq;
    float* base = attnw + ((size_t)(b * NSEQ + row)) * EMB + h * DH;
    base[l31]      = v0;
    base[32 + l31] = v1;
    __bf16* bb2 = attnw_bf + ((size_t)(b * NSEQ + row)) * EMB + h * DH;
    bb2[l31]      = f2bf(v0);
    bb2[32 + l31] = f2bf(v1);
  }
}

extern "C" void kernel_launch(void* const* d_in, const int* in_sizes, int n_in,
                              void* d_out, int out_size, void* d_ws, size_t ws_size,
                              hipStream_t stream) {
  const float* q  = (const float*)d_in[0];
  const float* Wq = (const float*)d_in[1];
  const float* bq = (const float*)d_in[2];
  const float* Wk = (const float*)d_in[3];
  const float* bk = (const float*)d_in[4];
  const float* Wv = (const float*)d_in[5];
  const float* bv = (const float*)d_in[6];
  const float* Wo = (const float*)d_in[7];
  const float* bo = (const float*)d_in[8];

  float* outp  = (float*)d_out;
  float* attnw = outp + MAT;            // second tuple element

  // ws = Q | K | Vt | Xbf(->attnw_bf) | Wbf[4]   (bf16; ~75.5 MB, fits: r7)
  __bf16* Qw   = (__bf16*)d_ws;
  __bf16* Kw   = Qw + MAT;
  __bf16* Vtw  = Qw + 2 * MAT;          // layout [EMB][BSEQ]
  __bf16* Xbf  = Qw + 3 * MAT;          // aliased as attnw_bf after qkv
  __bf16* Wbf  = Qw + 4 * MAT;

  const int xblocks = (int)(MAT / 4 / 256);
  const int wblocks = (int)(4 * WSZ / 4 / 256);
  cvt_all<<<xblocks + wblocks, 256, 0, stream>>>(q, Wq, Wk, Wv, Wo, Xbf, Wbf);

  qkv256<<<384, 512, 0, stream>>>(Xbf, Wbf, bq, bk, bv, Qw, Kw, Vtw);

  flash_kernel<<<dim3(8, NH, NB), 512, 0, stream>>>(Qw, Kw, Vtw, attnw, Xbf);

  oproj256<<<128, 512, 0, stream>>>(Xbf, Wbf + 3 * WSZ, bo, outp);
}

// Round 15
// 221.387 us; speedup vs baseline: 1.0646x; 1.0646x over previous
//
#include <hip/hip_runtime.h>

typedef float  f32x4  __attribute__((ext_vector_type(4)));
typedef float  f32x16 __attribute__((ext_vector_type(16)));
typedef __bf16 bf16x2 __attribute__((ext_vector_type(2)));
typedef __bf16 bf16x4 __attribute__((ext_vector_type(4)));
typedef __bf16 bf16x8 __attribute__((ext_vector_type(8)));
typedef unsigned int u32;
typedef u32 u32x4 __attribute__((ext_vector_type(4)));

#define MFMA16(a, b, c) __builtin_amdgcn_mfma_f32_16x16x32_bf16((a), (b), (c), 0, 0, 0)
#define MFMA32(a, b, c) __builtin_amdgcn_mfma_f32_32x32x16_bf16((a), (b), (c), 0, 0, 0)

constexpr int EMB  = 1024;
constexpr int NSEQ = 2048;
constexpr int NB   = 4;
constexpr int NH   = 16;
constexpr int DH   = 64;
constexpr size_t HSTRIDE = (size_t)NSEQ * DH;        // elements per head (Q/K)
constexpr size_t MAT     = (size_t)NB * NSEQ * EMB;  // 8388608
constexpr size_t WSZ     = (size_t)EMB * EMB;        // 1048576
constexpr int    BSEQ    = NB * NSEQ;                // 8192 (V^T row length)
constexpr float  QSCALE  = 0.18033688011112042f;     // 0.125 * log2(e)

__device__ __forceinline__ __bf16 f2bf(float f) { return (__bf16)f; }

__device__ __forceinline__ u32 pkbf(float a, float b) {
  bf16x2 t = {(__bf16)a, (__bf16)b};
  return __builtin_bit_cast(u32, t);
}

// XOR swizzle (involution) for 128B-row tiles: rows (bits 7-9) into 16B-slot bits (4-6).
__device__ __forceinline__ int swz(int a) { return a ^ (((a >> 7) & 7) << 4); }

// async global->LDS, 16B per lane; LDS dest = wave-uniform base + lane*16.
__device__ __forceinline__ void gll16(const void* g, void* l) {
  __builtin_amdgcn_global_load_lds((const __attribute__((address_space(1))) unsigned*)g,
                                   (__attribute__((address_space(3))) unsigned*)l, 16, 0, 0);
}

// ================= conversion pre-pass (single launch) =================
__global__ __launch_bounds__(256) void cvt_all(const float* __restrict__ x,
                                               const float* __restrict__ w0,
                                               const float* __restrict__ w1,
                                               const float* __restrict__ w2,
                                               const float* __restrict__ w3,
                                               __bf16* __restrict__ Xbf,
                                               __bf16* __restrict__ Wbf) {
  const int xblocks = (int)(MAT / 4 / 256);
  const int wslice  = (int)(WSZ / 4 / 256);
  const float* src;
  __bf16* dst;
  size_t idx;
  if (blockIdx.x < (unsigned)xblocks) {
    src = x; dst = Xbf;
    idx = (size_t)blockIdx.x * 256 + threadIdx.x;
  } else {
    int j = blockIdx.x - xblocks;
    int z = j / wslice, r = j % wslice;
    const float* srcs[4] = {w0, w1, w2, w3};
    src = srcs[z];
    dst = Wbf + (size_t)z * WSZ;
    idx = (size_t)r * 256 + threadIdx.x;
  }
  f32x4 v = *reinterpret_cast<const f32x4*>(src + idx * 4);
  bf16x4 o = {f2bf(v[0]), f2bf(v[1]), f2bf(v[2]), f2bf(v[3])};
  *reinterpret_cast<bf16x4*>(dst + idx * 4) = o;
}

// ================= fused 3-output QKV GEMM, 128x64 tile (r13 proven) =================
__global__ __launch_bounds__(256) void qkv3(const __bf16* __restrict__ Xbf,
                                            const __bf16* __restrict__ Wbf,
                                            const float* __restrict__ bq,
                                            const float* __restrict__ bk,
                                            const float* __restrict__ bv,
                                            __bf16* __restrict__ Qw,
                                            __bf16* __restrict__ Kw,
                                            __bf16* __restrict__ Vtw) {
  __shared__ __align__(16) __bf16 sA[128 * 64];        // 16KB
  __shared__ __align__(16) __bf16 sW[3][64 * 64];      // 3 x 8KB
  const int t = threadIdx.x;
  const int lane = t & 63, w = t >> 6;
  const int l15 = lane & 15, g = lane >> 4;

  // bijective XCD remap over 1024 blocks
  int flat = blockIdx.x + 16 * blockIdx.y;
  int logical = (flat & 7) * 128 + (flat >> 3);
  const int m0 = (logical >> 4) * 128, n0 = (logical & 15) * 64;

  const char* Ac  = (const char*)Xbf;
  const char* Wc[3] = {(const char*)(Wbf + 0 * WSZ),
                       (const char*)(Wbf + 1 * WSZ),
                       (const char*)(Wbf + 2 * WSZ)};

  const int srow = lane >> 3;                          // 8 rows / chunk
  const int scol = ((lane & 7) ^ srow) * 16;           // pre-swizzled source col byte

  int offA[2][2], offB[4][2];
#pragma unroll
  for (int i = 0; i < 2; ++i)
#pragma unroll
    for (int ks = 0; ks < 2; ++ks) {
      int ra = w * 32 + i * 16 + l15;
      offA[i][ks] = (ra * 128 + ((ks * 64 + g * 16) ^ ((l15 & 7) << 4))) >> 1;
    }
#pragma unroll
  for (int i = 0; i < 4; ++i)
#pragma unroll
    for (int ks = 0; ks < 2; ++ks) {
      int rb = i * 16 + l15;
      offB[i][ks] = (rb * 128 + ((ks * 64 + g * 16) ^ ((l15 & 7) << 4))) >> 1;
    }

  f32x4 acc[3][2][4];
#pragma unroll
  for (int m = 0; m < 3; ++m)
#pragma unroll
    for (int i = 0; i < 2; ++i)
#pragma unroll
      for (int j = 0; j < 4; ++j) acc[m][i][j] = f32x4{0.f, 0.f, 0.f, 0.f};

#pragma unroll 1
  for (int k0 = 0; k0 < EMB; k0 += 64) {
#pragma unroll
    for (int p = 0; p < 4; ++p) {
      int c = p * 4 + w;
      gll16(Ac + (size_t)(m0 + c * 8 + srow) * (EMB * 2) + k0 * 2 + scol, sA + c * 512);
    }
#pragma unroll
    for (int p = 0; p < 2; ++p) {
      int c = p * 4 + w;
      size_t rowB = (size_t)(n0 + c * 8 + srow) * (EMB * 2) + k0 * 2 + scol;
#pragma unroll
      for (int mat = 0; mat < 3; ++mat)
        gll16(Wc[mat] + rowB, &sW[mat][c * 512]);
    }
    __syncthreads();   // drains vmcnt: staged tiles visible
#pragma unroll
    for (int ks = 0; ks < 2; ++ks) {
      bf16x8 af[2];
#pragma unroll
      for (int i = 0; i < 2; ++i)
        af[i] = *reinterpret_cast<const bf16x8*>(&sA[offA[i][ks]]);
#pragma unroll
      for (int mat = 0; mat < 3; ++mat) {
        bf16x8 bf[4];
#pragma unroll
        for (int i = 0; i < 4; ++i)
          bf[i] = *reinterpret_cast<const bf16x8*>(&sW[mat][offB[i][ks]]);
#pragma unroll
        for (int mi = 0; mi < 2; ++mi)
#pragma unroll
          for (int ni = 0; ni < 4; ++ni)
            acc[mat][mi][ni] = MFMA16(af[mi], bf[ni], acc[mat][mi][ni]);
      }
    }
    __syncthreads();   // tiles consumed; safe to restage
  }

  // ---- epilogue ----  (C/D: row=(lane>>4)*4+reg, col=lane&15)
  const int hh = n0 >> 6;                              // one head per block
#pragma unroll
  for (int mi = 0; mi < 2; ++mi)
#pragma unroll
    for (int ni = 0; ni < 4; ++ni) {
      int cg = n0 + ni * 16 + l15;
      int d = cg & (DH - 1);
#pragma unroll
      for (int j = 0; j < 4; ++j) {
        int rg = m0 + w * 32 + mi * 16 + g * 4 + j;
        int bb = rg >> 11, r = rg & (NSEQ - 1);
        size_t hb = (size_t)(bb * NH + hh);
        size_t idx = (hb * NSEQ + r) * DH + d;
        Qw[idx] = f2bf((acc[0][mi][ni][j] + bq[cg]) * QSCALE);
        Kw[idx] = f2bf(acc[1][mi][ni][j] + bk[cg]);
      }
      float bvc = bv[cg];
      int rg0 = m0 + w * 32 + mi * 16 + g * 4;
      bf16x4 pv = {f2bf(acc[2][mi][ni][0] + bvc), f2bf(acc[2][mi][ni][1] + bvc),
                   f2bf(acc[2][mi][ni][2] + bvc), f2bf(acc[2][mi][ni][3] + bvc)};
      *reinterpret_cast<bf16x4*>(Vtw + (size_t)cg * BSEQ + rg0) = pv;
    }
}

// ================= output projection, 256(M)x128(N) tile =================
// 4 waves; wave w owns rows [w*64, w*64+64): acc[4][8] = 128 VGPR,
// 64 MFMA16 per wave per barrier-pair (2x the r13 oproj amortization).
// LDS 48KB single-buffered (A 32KB + B 16KB). Grid 256 blocks = 1/CU.
// Same 2-barrier sync structure as qkv3 (proven); bf loaded one-at-a-time.
__global__ __launch_bounds__(256) void oproj_bf(const __bf16* __restrict__ Abf,
                                                const __bf16* __restrict__ W,
                                                const float* __restrict__ bias,
                                                float* __restrict__ outp) {
  __shared__ __align__(16) __bf16 sA[256 * 64];        // 32KB
  __shared__ __align__(16) __bf16 sB[128 * 64];        // 16KB
  const int t = threadIdx.x;
  const int lane = t & 63, w = t >> 6;
  const int l15 = lane & 15, g = lane >> 4;

  // bijective XCD remap over 256 blocks: each XCD gets 32 consecutive
  // logicals = 4 m-tiles x all 8 n (A-panel 2MB + Wo 2MB per L2)
  int flat = blockIdx.x;
  int logical = (flat & 7) * 32 + (flat >> 3);
  const int m0 = (logical >> 3) * 256, n0 = (logical & 7) * 128;

  const char* Ac = (const char*)Abf;
  const char* Wc = (const char*)W;
  const int srow = lane >> 3;                          // 8 rows / chunk
  const int scol = ((lane & 7) ^ srow) * 16;           // pre-swizzled source col byte

  int offA[4][2], offB[8][2];
#pragma unroll
  for (int i = 0; i < 4; ++i)
#pragma unroll
    for (int ks = 0; ks < 2; ++ks) {
      int ra = w * 64 + i * 16 + l15;                  // within 256-row A tile
      offA[i][ks] = (ra * 128 + ((ks * 64 + g * 16) ^ ((l15 & 7) << 4))) >> 1;
    }
#pragma unroll
  for (int i = 0; i < 8; ++i)
#pragma unroll
    for (int ks = 0; ks < 2; ++ks) {
      int rb = i * 16 + l15;                           // within 128-row B tile
      offB[i][ks] = (rb * 128 + ((ks * 64 + g * 16) ^ ((l15 & 7) << 4))) >> 1;
    }

  f32x4 acc[4][8];
#pragma unroll
  for (int i = 0; i < 4; ++i)
#pragma unroll
    for (int j = 0; j < 8; ++j) acc[i][j] = f32x4{0.f, 0.f, 0.f, 0.f};

#pragma unroll 1
  for (int k0 = 0; k0 < EMB; k0 += 64) {
    // stage A: 32 chunks of 1KB (8 per wave); B: 16 chunks (4 per wave)
#pragma unroll
    for (int p = 0; p < 8; ++p) {
      int c = p * 4 + w;
      gll16(Ac + (size_t)(m0 + c * 8 + srow) * (EMB * 2) + k0 * 2 + scol, sA + c * 512);
    }
#pragma unroll
    for (int p = 0; p < 4; ++p) {
      int c = p * 4 + w;
      gll16(Wc + (size_t)(n0 + c * 8 + srow) * (EMB * 2) + k0 * 2 + scol, sB + c * 512);
    }
    __syncthreads();   // drains vmcnt: staged tiles visible
#pragma unroll
    for (int ks = 0; ks < 2; ++ks) {
      bf16x8 af[4];
#pragma unroll
      for (int i = 0; i < 4; ++i)
        af[i] = *reinterpret_cast<const bf16x8*>(&sA[offA[i][ks]]);
#pragma unroll
      for (int ni = 0; ni < 8; ++ni) {
        bf16x8 bf = *reinterpret_cast<const bf16x8*>(&sB[offB[ni][ks]]);
#pragma unroll
        for (int mi = 0; mi < 4; ++mi)
          acc[mi][ni] = MFMA16(af[mi], bf, acc[mi][ni]);
      }
    }
    __syncthreads();   // tiles consumed; safe to restage
  }

#pragma unroll
  for (int mi = 0; mi < 4; ++mi)
#pragma unroll
    for (int ni = 0; ni < 8; ++ni) {
      int cg = n0 + ni * 16 + l15;
      float bc = bias[cg];
#pragma unroll
      for (int j = 0; j < 4; ++j) {
        int rg = m0 + w * 64 + mi * 16 + g * 4 + j;
        outp[(size_t)rg * EMB + cg] = acc[mi][ni][j] + bc;
      }
    }
}

// ================= Flash attention (r13 proven, unchanged) =================
__global__ __launch_bounds__(512) void flash_kernel(const __bf16* __restrict__ Qb,
                                                    const __bf16* __restrict__ Kb,
                                                    const __bf16* __restrict__ Vtb,
                                                    float* __restrict__ attnw,
                                                    __bf16* __restrict__ attnw_bf) {
  __shared__ __align__(16) __bf16 lds[2][16384];  // [buf][ K:8192 | V:8192 ] elements
  const int t = threadIdx.x;
  const int lane = t & 63, w = t >> 6;            // w in [0,8)
  const int l31 = lane & 31, hi = lane >> 5;

  int flat = blockIdx.x + 8 * (blockIdx.y + NH * blockIdx.z);
  int logical = (flat & 7) * 64 + (flat >> 3);
  const int qt = logical & 7, h = (logical >> 3) & 15, b = logical >> 7;

  const size_t hoff = ((size_t)(b * NH + h)) * HSTRIDE;
  const __bf16* Qh = Qb + hoff;                  // [2048][64]
  const char* Kc = (const char*)(Kb + hoff);     // [2048][64]  row = 128 B
  const char* Vc = (const char*)(Vtb + (size_t)(h * DH) * BSEQ + (size_t)b * NSEQ);
  const int q0 = qt * 256 + w * 32;              // this wave's 32 q-rows

  bf16x8 qf[4];
#pragma unroll
  for (int ds = 0; ds < 4; ++ds)
    qf[ds] = *reinterpret_cast<const bf16x8*>(Qh + (size_t)(q0 + l31) * DH + ds * 16 + hi * 8);

  int koff[2][4], voff[4][2];
#pragma unroll
  for (int kt32 = 0; kt32 < 2; ++kt32)
#pragma unroll
    for (int ds = 0; ds < 4; ++ds)
      koff[kt32][ds] = swz((kt32 * 32 + l31) * 128 + ds * 32 + hi * 16) >> 1;
#pragma unroll
  for (int c = 0; c < 4; ++c)
#pragma unroll
    for (int db = 0; db < 2; ++db)
      voff[c][db] = swz((db * 32 + l31) * 128 + c * 32 + hi * 16) >> 1;

  // stage a 128-kv tile (K 16KB + V 16KB); V row stride = BSEQ*2 = 16KB
  auto stage = [&](int bf, int kt) {
#pragma unroll
    for (int hh = 0; hh < 2; ++hh) {
      int L = w * 1024 + lane * 16;
      int s = swz(L);
      gll16(Kc + (size_t)(kt + hh * 64) * 128 + s, &lds[bf][hh * 4096 + w * 512]);
      int d = s >> 7, rem = s & 127;
      gll16(Vc + (size_t)d * (BSEQ * 2) + (kt + hh * 64) * 2 + rem,
            &lds[bf][8192 + hh * 4096 + w * 512]);
    }
  };

  f32x16 o0{}, o1{}, osum{};
  const f32x16 kZero{};                 // hoisted zero C operand
  bf16x8 vones;
#pragma unroll
  for (int i = 0; i < 8; ++i) vones[i] = (__bf16)1.0f;

  stage(0, 0);
  __syncthreads();

#pragma unroll 1
  for (int it = 0; it < NSEQ / 128; ++it) {
    const int cur = it & 1;
    if (it + 1 < NSEQ / 128) stage(cur ^ 1, (it + 1) * 128);

#pragma unroll
    for (int sub = 0; sub < 2; ++sub) {
      const __bf16* Kl = lds[cur] + sub * 4096;
      const __bf16* Vl = lds[cur] + 8192 + sub * 4096;

      bf16x8 kf[2][4];
#pragma unroll
      for (int kt32 = 0; kt32 < 2; ++kt32)
#pragma unroll
        for (int ds = 0; ds < 4; ++ds)
          kf[kt32][ds] = *reinterpret_cast<const bf16x8*>(Kl + koff[kt32][ds]);

      f32x16 s0, s1;
      __builtin_amdgcn_s_setprio(1);
      s0 = MFMA32(kf[0][0], qf[0], kZero);
      s1 = MFMA32(kf[1][0], qf[0], kZero);
#pragma unroll
      for (int ds = 1; ds < 4; ++ds) s0 = MFMA32(kf[0][ds], qf[ds], s0);
#pragma unroll
      for (int ds = 1; ds < 4; ++ds) s1 = MFMA32(kf[1][ds], qf[ds], s1);
      __builtin_amdgcn_s_setprio(0);

      bf16x8 vf[4][2];
#pragma unroll
      for (int c = 0; c < 4; ++c)
#pragma unroll
        for (int db = 0; db < 2; ++db)
          vf[c][db] = *reinterpret_cast<const bf16x8*>(Vl + voff[c][db]);

#pragma unroll
      for (int r = 0; r < 16; ++r) s0[r] = __builtin_exp2f(s0[r]);
#pragma unroll
      for (int r = 0; r < 16; ++r) s1[r] = __builtin_exp2f(s1[r]);

      u32 pk0[8], pk1[8];
#pragma unroll
      for (int j = 0; j < 8; ++j) pk0[j] = pkbf(s0[2 * j], s0[2 * j + 1]);
#pragma unroll
      for (int j = 0; j < 8; ++j) pk1[j] = pkbf(s1[2 * j], s1[2 * j + 1]);

      auto pv_step = [&](u32& a0, u32& a1, u32& a2, u32& a3, int c) {
        asm("v_permlane32_swap_b32 %0, %1" : "+v"(a0), "+v"(a2));
        asm("v_permlane32_swap_b32 %0, %1" : "+v"(a1), "+v"(a3));
        u32x4 wv = {a0, a1, a2, a3};
        bf16x8 pa = __builtin_bit_cast(bf16x8, wv);
        o0 = MFMA32(pa, vf[c][0], o0);
        o1 = MFMA32(pa, vf[c][1], o1);
        osum = MFMA32(pa, vones, osum);
      };
      __builtin_amdgcn_s_setprio(1);
      pv_step(pk0[0], pk0[1], pk0[2], pk0[3], 0);
      pv_step(pk0[4], pk0[5], pk0[6], pk0[7], 1);
      pv_step(pk1[0], pk1[1], pk1[2], pk1[3], 2);
      pv_step(pk1[4], pk1[5], pk1[6], pk1[7], 3);
      __builtin_amdgcn_s_setprio(0);
    }

    __syncthreads();   // drains staging vmcnt + lgkm; safe buffer flip
  }

#pragma unroll
  for (int r = 0; r < 16; ++r) {
    int qq = (r & 3) + 8 * (r >> 2) + 4 * hi;
    float invq = 1.0f / osum[r];
    int row = q0 + qq;
    float v0 = o0[r] * invq, v1 = o1[r] * invq;
    float* base = attnw + ((size_t)(b * NSEQ + row)) * EMB + h * DH;
    base[l31]      = v0;
    base[32 + l31] = v1;
    __bf16* bb2 = attnw_bf + ((size_t)(b * NSEQ + row)) * EMB + h * DH;
    bb2[l31]      = f2bf(v0);
    bb2[32 + l31] = f2bf(v1);
  }
}

extern "C" void kernel_launch(void* const* d_in, const int* in_sizes, int n_in,
                              void* d_out, int out_size, void* d_ws, size_t ws_size,
                              hipStream_t stream) {
  const float* q  = (const float*)d_in[0];
  const float* Wq = (const float*)d_in[1];
  const float* bq = (const float*)d_in[2];
  const float* Wk = (const float*)d_in[3];
  const float* bk = (const float*)d_in[4];
  const float* Wv = (const float*)d_in[5];
  const float* bv = (const float*)d_in[6];
  const float* Wo = (const float*)d_in[7];
  const float* bo = (const float*)d_in[8];

  float* outp  = (float*)d_out;
  float* attnw = outp + MAT;            // second tuple element

  // ws = Q | K | Vt | Xbf(->attnw_bf) | Wbf[4]   (bf16; ~75.5 MB, fits: r7)
  __bf16* Qw   = (__bf16*)d_ws;
  __bf16* Kw   = Qw + MAT;
  __bf16* Vtw  = Qw + 2 * MAT;          // layout [EMB][BSEQ]
  __bf16* Xbf  = Qw + 3 * MAT;          // aliased as attnw_bf after qkv
  __bf16* Wbf  = Qw + 4 * MAT;

  const int xblocks = (int)(MAT / 4 / 256);
  const int wblocks = (int)(4 * WSZ / 4 / 256);
  cvt_all<<<xblocks + wblocks, 256, 0, stream>>>(q, Wq, Wk, Wv, Wo, Xbf, Wbf);

  qkv3<<<dim3(16, 64), 256, 0, stream>>>(Xbf, Wbf, bq, bk, bv, Qw, Kw, Vtw);

  flash_kernel<<<dim3(8, NH, NB), 512, 0, stream>>>(Qw, Kw, Vtw, attnw, Xbf);

  oproj_bf<<<256, 256, 0, stream>>>(Xbf, Wbf + 3 * WSZ, bo, outp);
}

// Round 16
// 213.835 us; speedup vs baseline: 1.1022x; 1.0353x over previous
//
#include <hip/hip_runtime.h>

typedef float  f32x4  __attribute__((ext_vector_type(4)));
typedef float  f32x16 __attribute__((ext_vector_type(16)));
typedef __bf16 bf16x2 __attribute__((ext_vector_type(2)));
typedef __bf16 bf16x4 __attribute__((ext_vector_type(4)));
typedef __bf16 bf16x8 __attribute__((ext_vector_type(8)));
typedef unsigned int u32;
typedef u32 u32x4 __attribute__((ext_vector_type(4)));

#define MFMA16(a, b, c) __builtin_amdgcn_mfma_f32_16x16x32_bf16((a), (b), (c), 0, 0, 0)
#define MFMA32(a, b, c) __builtin_amdgcn_mfma_f32_32x32x16_bf16((a), (b), (c), 0, 0, 0)

constexpr int EMB  = 1024;
constexpr int NSEQ = 2048;
constexpr int NB   = 4;
constexpr int NH   = 16;
constexpr int DH   = 64;
constexpr size_t HSTRIDE = (size_t)NSEQ * DH;        // elements per head (Q/K)
constexpr size_t MAT     = (size_t)NB * NSEQ * EMB;  // 8388608
constexpr size_t WSZ     = (size_t)EMB * EMB;        // 1048576
constexpr int    BSEQ    = NB * NSEQ;                // 8192 (V^T row length)
constexpr float  QSCALE  = 0.18033688011112042f;     // 0.125 * log2(e)

__device__ __forceinline__ __bf16 f2bf(float f) { return (__bf16)f; }

__device__ __forceinline__ u32 pkbf(float a, float b) {
  bf16x2 t = {(__bf16)a, (__bf16)b};
  return __builtin_bit_cast(u32, t);
}

// XOR swizzle (involution) for 128B-row tiles: rows (bits 7-9) into 16B-slot bits (4-6).
__device__ __forceinline__ int swz(int a) { return a ^ (((a >> 7) & 7) << 4); }

// async global->LDS, 16B per lane; LDS dest = wave-uniform base + lane*16.
__device__ __forceinline__ void gll16(const void* g, void* l) {
  __builtin_amdgcn_global_load_lds((const __attribute__((address_space(1))) unsigned*)g,
                                   (__attribute__((address_space(3))) unsigned*)l, 16, 0, 0);
}

// ================= conversion pre-pass (single launch) =================
__global__ __launch_bounds__(256) void cvt_all(const float* __restrict__ x,
                                               const float* __restrict__ w0,
                                               const float* __restrict__ w1,
                                               const float* __restrict__ w2,
                                               const float* __restrict__ w3,
                                               __bf16* __restrict__ Xbf,
                                               __bf16* __restrict__ Wbf) {
  const int xblocks = (int)(MAT / 4 / 256);
  const int wslice  = (int)(WSZ / 4 / 256);
  const float* src;
  __bf16* dst;
  size_t idx;
  if (blockIdx.x < (unsigned)xblocks) {
    src = x; dst = Xbf;
    idx = (size_t)blockIdx.x * 256 + threadIdx.x;
  } else {
    int j = blockIdx.x - xblocks;
    int z = j / wslice, r = j % wslice;
    const float* srcs[4] = {w0, w1, w2, w3};
    src = srcs[z];
    dst = Wbf + (size_t)z * WSZ;
    idx = (size_t)r * 256 + threadIdx.x;
  }
  f32x4 v = *reinterpret_cast<const f32x4*>(src + idx * 4);
  bf16x4 o = {f2bf(v[0]), f2bf(v[1]), f2bf(v[2]), f2bf(v[3])};
  *reinterpret_cast<bf16x4*>(dst + idx * 4) = o;
}

// ================= fused 3-output QKV GEMM, 128x64 tile (r13 proven) =================
__global__ __launch_bounds__(256) void qkv3(const __bf16* __restrict__ Xbf,
                                            const __bf16* __restrict__ Wbf,
                                            const float* __restrict__ bq,
                                            const float* __restrict__ bk,
                                            const float* __restrict__ bv,
                                            __bf16* __restrict__ Qw,
                                            __bf16* __restrict__ Kw,
                                            __bf16* __restrict__ Vtw) {
  __shared__ __align__(16) __bf16 sA[128 * 64];        // 16KB
  __shared__ __align__(16) __bf16 sW[3][64 * 64];      // 3 x 8KB
  const int t = threadIdx.x;
  const int lane = t & 63, w = t >> 6;
  const int l15 = lane & 15, g = lane >> 4;

  // bijective XCD remap over 1024 blocks
  int flat = blockIdx.x + 16 * blockIdx.y;
  int logical = (flat & 7) * 128 + (flat >> 3);
  const int m0 = (logical >> 4) * 128, n0 = (logical & 15) * 64;

  const char* Ac  = (const char*)Xbf;
  const char* Wc[3] = {(const char*)(Wbf + 0 * WSZ),
                       (const char*)(Wbf + 1 * WSZ),
                       (const char*)(Wbf + 2 * WSZ)};

  const int srow = lane >> 3;                          // 8 rows / chunk
  const int scol = ((lane & 7) ^ srow) * 16;           // pre-swizzled source col byte

  int offA[2][2], offB[4][2];
#pragma unroll
  for (int i = 0; i < 2; ++i)
#pragma unroll
    for (int ks = 0; ks < 2; ++ks) {
      int ra = w * 32 + i * 16 + l15;
      offA[i][ks] = (ra * 128 + ((ks * 64 + g * 16) ^ ((l15 & 7) << 4))) >> 1;
    }
#pragma unroll
  for (int i = 0; i < 4; ++i)
#pragma unroll
    for (int ks = 0; ks < 2; ++ks) {
      int rb = i * 16 + l15;
      offB[i][ks] = (rb * 128 + ((ks * 64 + g * 16) ^ ((l15 & 7) << 4))) >> 1;
    }

  f32x4 acc[3][2][4];
#pragma unroll
  for (int m = 0; m < 3; ++m)
#pragma unroll
    for (int i = 0; i < 2; ++i)
#pragma unroll
      for (int j = 0; j < 4; ++j) acc[m][i][j] = f32x4{0.f, 0.f, 0.f, 0.f};

#pragma unroll 1
  for (int k0 = 0; k0 < EMB; k0 += 64) {
#pragma unroll
    for (int p = 0; p < 4; ++p) {
      int c = p * 4 + w;
      gll16(Ac + (size_t)(m0 + c * 8 + srow) * (EMB * 2) + k0 * 2 + scol, sA + c * 512);
    }
#pragma unroll
    for (int p = 0; p < 2; ++p) {
      int c = p * 4 + w;
      size_t rowB = (size_t)(n0 + c * 8 + srow) * (EMB * 2) + k0 * 2 + scol;
#pragma unroll
      for (int mat = 0; mat < 3; ++mat)
        gll16(Wc[mat] + rowB, &sW[mat][c * 512]);
    }
    __syncthreads();   // drains vmcnt: staged tiles visible
#pragma unroll
    for (int ks = 0; ks < 2; ++ks) {
      bf16x8 af[2];
#pragma unroll
      for (int i = 0; i < 2; ++i)
        af[i] = *reinterpret_cast<const bf16x8*>(&sA[offA[i][ks]]);
#pragma unroll
      for (int mat = 0; mat < 3; ++mat) {
        bf16x8 bf[4];
#pragma unroll
        for (int i = 0; i < 4; ++i)
          bf[i] = *reinterpret_cast<const bf16x8*>(&sW[mat][offB[i][ks]]);
#pragma unroll
        for (int mi = 0; mi < 2; ++mi)
#pragma unroll
          for (int ni = 0; ni < 4; ++ni)
            acc[mat][mi][ni] = MFMA16(af[mi], bf[ni], acc[mat][mi][ni]);
      }
    }
    __syncthreads();   // tiles consumed; safe to restage
  }

  // ---- epilogue ----  (C/D: row=(lane>>4)*4+reg, col=lane&15)
  const int hh = n0 >> 6;                              // one head per block
#pragma unroll
  for (int mi = 0; mi < 2; ++mi)
#pragma unroll
    for (int ni = 0; ni < 4; ++ni) {
      int cg = n0 + ni * 16 + l15;
      int d = cg & (DH - 1);
#pragma unroll
      for (int j = 0; j < 4; ++j) {
        int rg = m0 + w * 32 + mi * 16 + g * 4 + j;
        int bb = rg >> 11, r = rg & (NSEQ - 1);
        size_t hb = (size_t)(bb * NH + hh);
        size_t idx = (hb * NSEQ + r) * DH + d;
        Qw[idx] = f2bf((acc[0][mi][ni][j] + bq[cg]) * QSCALE);
        Kw[idx] = f2bf(acc[1][mi][ni][j] + bk[cg]);
      }
      float bvc = bv[cg];
      int rg0 = m0 + w * 32 + mi * 16 + g * 4;
      bf16x4 pv = {f2bf(acc[2][mi][ni][0] + bvc), f2bf(acc[2][mi][ni][1] + bvc),
                   f2bf(acc[2][mi][ni][2] + bvc), f2bf(acc[2][mi][ni][3] + bvc)};
      *reinterpret_cast<bf16x4*>(Vtw + (size_t)cg * BSEQ + rg0) = pv;
    }
}

// ================= output projection (r13 proven: 128x128, 512 blocks = 2/CU) =================
__device__ __forceinline__ void gemm_loop(__bf16* sA, __bf16* sB,
                                          const __bf16* __restrict__ A,
                                          const __bf16* __restrict__ W,
                                          int m0, int n0, f32x4 (&acc)[4][4]) {
  const int t = threadIdx.x;
  const int lane = t & 63, w = t >> 6;
  const int wr = w >> 1, wc = w & 1;
  const int l15 = lane & 15, g = lane >> 4;
  const char* Ac = (const char*)A;
  const char* Wc = (const char*)W;
  const int srow = lane >> 3;
  const int scol = ((lane & 7) ^ srow) * 16;

  int offA[4][2], offB[4][2];
#pragma unroll
  for (int i = 0; i < 4; ++i)
#pragma unroll
    for (int ks = 0; ks < 2; ++ks) {
      int ra = wr * 64 + i * 16 + l15;
      int rb = wc * 64 + i * 16 + l15;
      offA[i][ks] = (ra * 128 + ((ks * 64 + g * 16) ^ ((l15 & 7) << 4))) >> 1;
      offB[i][ks] = (rb * 128 + ((ks * 64 + g * 16) ^ ((l15 & 7) << 4))) >> 1;
    }

#pragma unroll 1
  for (int k0 = 0; k0 < EMB; k0 += 64) {
#pragma unroll
    for (int p = 0; p < 4; ++p) {
      int c = p * 4 + w;
      gll16(Ac + (size_t)(m0 + c * 8 + srow) * (EMB * 2) + k0 * 2 + scol, sA + c * 512);
      gll16(Wc + (size_t)(n0 + c * 8 + srow) * (EMB * 2) + k0 * 2 + scol, sB + c * 512);
    }
    __syncthreads();
    bf16x8 af[4][2], bfr[4][2];
#pragma unroll
    for (int i = 0; i < 4; ++i)
#pragma unroll
      for (int ks = 0; ks < 2; ++ks) {
        af[i][ks]  = *reinterpret_cast<const bf16x8*>(sA + offA[i][ks]);
        bfr[i][ks] = *reinterpret_cast<const bf16x8*>(sB + offB[i][ks]);
      }
#pragma unroll
    for (int ks = 0; ks < 2; ++ks)
#pragma unroll
      for (int mi = 0; mi < 4; ++mi)
#pragma unroll
        for (int ni = 0; ni < 4; ++ni)
          acc[mi][ni] = MFMA16(af[mi][ks], bfr[ni][ks], acc[mi][ni]);
    __syncthreads();
  }
}

__global__ __launch_bounds__(256) void oproj_bf(const __bf16* __restrict__ Abf,
                                                const __bf16* __restrict__ W,
                                                const float* __restrict__ bias,
                                                float* __restrict__ outp) {
  __shared__ __align__(16) __bf16 smem[2][128 * 64];
  int flat = blockIdx.x + 8 * blockIdx.y;
  int logical = (flat & 7) * 64 + (flat >> 3);
  const int m0 = (logical >> 3) * 128, n0 = (logical & 7) * 128;

  f32x4 acc[4][4];
#pragma unroll
  for (int i = 0; i < 4; ++i)
#pragma unroll
    for (int j = 0; j < 4; ++j) acc[i][j] = f32x4{0.f, 0.f, 0.f, 0.f};

  gemm_loop(smem[0], smem[1], Abf, W, m0, n0, acc);

  const int lane = threadIdx.x & 63, w = threadIdx.x >> 6;
  const int wr = w >> 1, wc = w & 1, l15 = lane & 15, g = lane >> 4;
#pragma unroll
  for (int mi = 0; mi < 4; ++mi)
#pragma unroll
    for (int ni = 0; ni < 4; ++ni)
#pragma unroll
      for (int j = 0; j < 4; ++j) {
        int rg = m0 + wr * 64 + mi * 16 + g * 4 + j;
        int cg = n0 + wc * 64 + ni * 16 + l15;
        outp[(size_t)rg * EMB + cg] = acc[mi][ni][j] + bias[cg];
      }
}

// ================= Flash attention (r13 proven, unchanged) =================
__global__ __launch_bounds__(512) void flash_kernel(const __bf16* __restrict__ Qb,
                                                    const __bf16* __restrict__ Kb,
                                                    const __bf16* __restrict__ Vtb,
                                                    float* __restrict__ attnw,
                                                    __bf16* __restrict__ attnw_bf) {
  __shared__ __align__(16) __bf16 lds[2][16384];  // [buf][ K:8192 | V:8192 ] elements
  const int t = threadIdx.x;
  const int lane = t & 63, w = t >> 6;            // w in [0,8)
  const int l31 = lane & 31, hi = lane >> 5;

  int flat = blockIdx.x + 8 * (blockIdx.y + NH * blockIdx.z);
  int logical = (flat & 7) * 64 + (flat >> 3);
  const int qt = logical & 7, h = (logical >> 3) & 15, b = logical >> 7;

  const size_t hoff = ((size_t)(b * NH + h)) * HSTRIDE;
  const __bf16* Qh = Qb + hoff;                  // [2048][64]
  const char* Kc = (const char*)(Kb + hoff);     // [2048][64]  row = 128 B
  const char* Vc = (const char*)(Vtb + (size_t)(h * DH) * BSEQ + (size_t)b * NSEQ);
  const int q0 = qt * 256 + w * 32;              // this wave's 32 q-rows

  bf16x8 qf[4];
#pragma unroll
  for (int ds = 0; ds < 4; ++ds)
    qf[ds] = *reinterpret_cast<const bf16x8*>(Qh + (size_t)(q0 + l31) * DH + ds * 16 + hi * 8);

  int koff[2][4], voff[4][2];
#pragma unroll
  for (int kt32 = 0; kt32 < 2; ++kt32)
#pragma unroll
    for (int ds = 0; ds < 4; ++ds)
      koff[kt32][ds] = swz((kt32 * 32 + l31) * 128 + ds * 32 + hi * 16) >> 1;
#pragma unroll
  for (int c = 0; c < 4; ++c)
#pragma unroll
    for (int db = 0; db < 2; ++db)
      voff[c][db] = swz((db * 32 + l31) * 128 + c * 32 + hi * 16) >> 1;

  // stage a 128-kv tile (K 16KB + V 16KB); V row stride = BSEQ*2 = 16KB
  auto stage = [&](int bf, int kt) {
#pragma unroll
    for (int hh = 0; hh < 2; ++hh) {
      int L = w * 1024 + lane * 16;
      int s = swz(L);
      gll16(Kc + (size_t)(kt + hh * 64) * 128 + s, &lds[bf][hh * 4096 + w * 512]);
      int d = s >> 7, rem = s & 127;
      gll16(Vc + (size_t)d * (BSEQ * 2) + (kt + hh * 64) * 2 + rem,
            &lds[bf][8192 + hh * 4096 + w * 512]);
    }
  };

  f32x16 o0{}, o1{}, osum{};
  const f32x16 kZero{};                 // hoisted zero C operand
  bf16x8 vones;
#pragma unroll
  for (int i = 0; i < 8; ++i) vones[i] = (__bf16)1.0f;

  stage(0, 0);
  __syncthreads();

#pragma unroll 1
  for (int it = 0; it < NSEQ / 128; ++it) {
    const int cur = it & 1;
    if (it + 1 < NSEQ / 128) stage(cur ^ 1, (it + 1) * 128);

#pragma unroll
    for (int sub = 0; sub < 2; ++sub) {
      const __bf16* Kl = lds[cur] + sub * 4096;
      const __bf16* Vl = lds[cur] + 8192 + sub * 4096;

      bf16x8 kf[2][4];
#pragma unroll
      for (int kt32 = 0; kt32 < 2; ++kt32)
#pragma unroll
        for (int ds = 0; ds < 4; ++ds)
          kf[kt32][ds] = *reinterpret_cast<const bf16x8*>(Kl + koff[kt32][ds]);

      f32x16 s0, s1;
      __builtin_amdgcn_s_setprio(1);
      s0 = MFMA32(kf[0][0], qf[0], kZero);
      s1 = MFMA32(kf[1][0], qf[0], kZero);
#pragma unroll
      for (int ds = 1; ds < 4; ++ds) s0 = MFMA32(kf[0][ds], qf[ds], s0);
#pragma unroll
      for (int ds = 1; ds < 4; ++ds) s1 = MFMA32(kf[1][ds], qf[ds], s1);
      __builtin_amdgcn_s_setprio(0);

      bf16x8 vf[4][2];
#pragma unroll
      for (int c = 0; c < 4; ++c)
#pragma unroll
        for (int db = 0; db < 2; ++db)
          vf[c][db] = *reinterpret_cast<const bf16x8*>(Vl + voff[c][db]);

#pragma unroll
      for (int r = 0; r < 16; ++r) s0[r] = __builtin_exp2f(s0[r]);
#pragma unroll
      for (int r = 0; r < 16; ++r) s1[r] = __builtin_exp2f(s1[r]);

      u32 pk0[8], pk1[8];
#pragma unroll
      for (int j = 0; j < 8; ++j) pk0[j] = pkbf(s0[2 * j], s0[2 * j + 1]);
#pragma unroll
      for (int j = 0; j < 8; ++j) pk1[j] = pkbf(s1[2 * j], s1[2 * j + 1]);

      auto pv_step = [&](u32& a0, u32& a1, u32& a2, u32& a3, int c) {
        asm("v_permlane32_swap_b32 %0, %1" : "+v"(a0), "+v"(a2));
        asm("v_permlane32_swap_b32 %0, %1" : "+v"(a1), "+v"(a3));
        u32x4 wv = {a0, a1, a2, a3};
        bf16x8 pa = __builtin_bit_cast(bf16x8, wv);
        o0 = MFMA32(pa, vf[c][0], o0);
        o1 = MFMA32(pa, vf[c][1], o1);
        osum = MFMA32(pa, vones, osum);
      };
      __builtin_amdgcn_s_setprio(1);
      pv_step(pk0[0], pk0[1], pk0[2], pk0[3], 0);
      pv_step(pk0[4], pk0[5], pk0[6], pk0[7], 1);
      pv_step(pk1[0], pk1[1], pk1[2], pk1[3], 2);
      pv_step(pk1[4], pk1[5], pk1[6], pk1[7], 3);
      __builtin_amdgcn_s_setprio(0);
    }

    __syncthreads();   // drains staging vmcnt + lgkm; safe buffer flip
  }

#pragma unroll
  for (int r = 0; r < 16; ++r) {
    int qq = (r & 3) + 8 * (r >> 2) + 4 * hi;
    float invq = 1.0f / osum[r];
    int row = q0 + qq;
    float v0 = o0[r] * invq, v1 = o1[r] * invq;
    float* base = attnw + ((size_t)(b * NSEQ + row)) * EMB + h * DH;
    base[l31]      = v0;
    base[32 + l31] = v1;
    __bf16* bb2 = attnw_bf + ((size_t)(b * NSEQ + row)) * EMB + h * DH;
    bb2[l31]      = f2bf(v0);
    bb2[32 + l31] = f2bf(v1);
  }
}

extern "C" void kernel_launch(void* const* d_in, const int* in_sizes, int n_in,
                              void* d_out, int out_size, void* d_ws, size_t ws_size,
                              hipStream_t stream) {
  const float* q  = (const float*)d_in[0];
  const float* Wq = (const float*)d_in[1];
  const float* bq = (const float*)d_in[2];
  const float* Wk = (const float*)d_in[3];
  const float* bk = (const float*)d_in[4];
  const float* Wv = (const float*)d_in[5];
  const float* bv = (const float*)d_in[6];
  const float* Wo = (const float*)d_in[7];
  const float* bo = (const float*)d_in[8];

  float* outp  = (float*)d_out;
  float* attnw = outp + MAT;            // second tuple element

  // ws = Q | K | Vt | Xbf(->attnw_bf) | Wbf[4]   (bf16; ~75.5 MB, fits: r7)
  __bf16* Qw   = (__bf16*)d_ws;
  __bf16* Kw   = Qw + MAT;
  __bf16* Vtw  = Qw + 2 * MAT;          // layout [EMB][BSEQ]
  __bf16* Xbf  = Qw + 3 * MAT;          // aliased as attnw_bf after qkv
  __bf16* Wbf  = Qw + 4 * MAT;

  const int xblocks = (int)(MAT / 4 / 256);
  const int wblocks = (int)(4 * WSZ / 4 / 256);
  cvt_all<<<xblocks + wblocks, 256, 0, stream>>>(q, Wq, Wk, Wv, Wo, Xbf, Wbf);

  qkv3<<<dim3(16, 64), 256, 0, stream>>>(Xbf, Wbf, bq, bk, bv, Qw, Kw, Vtw);

  flash_kernel<<<dim3(8, NH, NB), 512, 0, stream>>>(Qw, Kw, Vtw, attnw, Xbf);

  oproj_bf<<<dim3(8, 64), 256, 0, stream>>>(Xbf, Wbf + 3 * WSZ, bo, outp);
}

// Round 17
// 188.356 us; speedup vs baseline: 1.2513x; 1.1353x over previous
//
#include <hip/hip_runtime.h>

typedef float  f32x4  __attribute__((ext_vector_type(4)));
typedef float  f32x16 __attribute__((ext_vector_type(16)));
typedef __bf16 bf16x2 __attribute__((ext_vector_type(2)));
typedef __bf16 bf16x4 __attribute__((ext_vector_type(4)));
typedef __bf16 bf16x8 __attribute__((ext_vector_type(8)));
typedef unsigned int u32;
typedef u32 u32x4 __attribute__((ext_vector_type(4)));

#define MFMA16(a, b, c) __builtin_amdgcn_mfma_f32_16x16x32_bf16((a), (b), (c), 0, 0, 0)
#define MFMA32(a, b, c) __builtin_amdgcn_mfma_f32_32x32x16_bf16((a), (b), (c), 0, 0, 0)

constexpr int EMB  = 1024;
constexpr int NSEQ = 2048;
constexpr int NB   = 4;
constexpr int NH   = 16;
constexpr int DH   = 64;
constexpr size_t HSTRIDE = (size_t)NSEQ * DH;        // elements per head (Q/K)
constexpr size_t MAT     = (size_t)NB * NSEQ * EMB;  // 8388608
constexpr size_t WSZ     = (size_t)EMB * EMB;        // 1048576
constexpr int    BSEQ    = NB * NSEQ;                // 8192 (V^T row length)
constexpr float  QSCALE  = 0.18033688011112042f;     // 0.125 * log2(e)

__device__ __forceinline__ __bf16 f2bf(float f) { return (__bf16)f; }

__device__ __forceinline__ u32 pkbf(float a, float b) {
  bf16x2 t = {(__bf16)a, (__bf16)b};
  return __builtin_bit_cast(u32, t);
}

// XOR swizzle (involution) for 128B-row tiles: rows (bits 7-9) into 16B-slot bits (4-6).
__device__ __forceinline__ int swz(int a) { return a ^ (((a >> 7) & 7) << 4); }

// async global->LDS, 16B per lane; LDS dest = wave-uniform base + lane*16.
__device__ __forceinline__ void gll16(const void* g, void* l) {
  __builtin_amdgcn_global_load_lds((const __attribute__((address_space(1))) unsigned*)g,
                                   (__attribute__((address_space(3))) unsigned*)l, 16, 0, 0);
}

// ================= conversion pre-pass (single launch) =================
__global__ __launch_bounds__(256) void cvt_all(const float* __restrict__ x,
                                               const float* __restrict__ w0,
                                               const float* __restrict__ w1,
                                               const float* __restrict__ w2,
                                               const float* __restrict__ w3,
                                               __bf16* __restrict__ Xbf,
                                               __bf16* __restrict__ Wbf) {
  const int xblocks = (int)(MAT / 4 / 256);
  const int wslice  = (int)(WSZ / 4 / 256);
  const float* src;
  __bf16* dst;
  size_t idx;
  if (blockIdx.x < (unsigned)xblocks) {
    src = x; dst = Xbf;
    idx = (size_t)blockIdx.x * 256 + threadIdx.x;
  } else {
    int j = blockIdx.x - xblocks;
    int z = j / wslice, r = j % wslice;
    const float* srcs[4] = {w0, w1, w2, w3};
    src = srcs[z];
    dst = Wbf + (size_t)z * WSZ;
    idx = (size_t)r * 256 + threadIdx.x;
  }
  f32x4 v = *reinterpret_cast<const f32x4*>(src + idx * 4);
  bf16x4 o = {f2bf(v[0]), f2bf(v[1]), f2bf(v[2]), f2bf(v[3])};
  *reinterpret_cast<bf16x4*>(dst + idx * 4) = o;
}

// ================= fused 3-output QKV GEMM, 128x64 tile (r13 proven) =================
__global__ __launch_bounds__(256) void qkv3(const __bf16* __restrict__ Xbf,
                                            const __bf16* __restrict__ Wbf,
                                            const float* __restrict__ bq,
                                            const float* __restrict__ bk,
                                            const float* __restrict__ bv,
                                            __bf16* __restrict__ Qw,
                                            __bf16* __restrict__ Kw,
                                            __bf16* __restrict__ Vtw) {
  __shared__ __align__(16) __bf16 sA[128 * 64];        // 16KB
  __shared__ __align__(16) __bf16 sW[3][64 * 64];      // 3 x 8KB
  const int t = threadIdx.x;
  const int lane = t & 63, w = t >> 6;
  const int l15 = lane & 15, g = lane >> 4;

  // bijective XCD remap over 1024 blocks
  int flat = blockIdx.x + 16 * blockIdx.y;
  int logical = (flat & 7) * 128 + (flat >> 3);
  const int m0 = (logical >> 4) * 128, n0 = (logical & 15) * 64;

  const char* Ac  = (const char*)Xbf;
  const char* Wc[3] = {(const char*)(Wbf + 0 * WSZ),
                       (const char*)(Wbf + 1 * WSZ),
                       (const char*)(Wbf + 2 * WSZ)};

  const int srow = lane >> 3;                          // 8 rows / chunk
  const int scol = ((lane & 7) ^ srow) * 16;           // pre-swizzled source col byte

  int offA[2][2], offB[4][2];
#pragma unroll
  for (int i = 0; i < 2; ++i)
#pragma unroll
    for (int ks = 0; ks < 2; ++ks) {
      int ra = w * 32 + i * 16 + l15;
      offA[i][ks] = (ra * 128 + ((ks * 64 + g * 16) ^ ((l15 & 7) << 4))) >> 1;
    }
#pragma unroll
  for (int i = 0; i < 4; ++i)
#pragma unroll
    for (int ks = 0; ks < 2; ++ks) {
      int rb = i * 16 + l15;
      offB[i][ks] = (rb * 128 + ((ks * 64 + g * 16) ^ ((l15 & 7) << 4))) >> 1;
    }

  f32x4 acc[3][2][4];
#pragma unroll
  for (int m = 0; m < 3; ++m)
#pragma unroll
    for (int i = 0; i < 2; ++i)
#pragma unroll
      for (int j = 0; j < 4; ++j) acc[m][i][j] = f32x4{0.f, 0.f, 0.f, 0.f};

#pragma unroll 1
  for (int k0 = 0; k0 < EMB; k0 += 64) {
#pragma unroll
    for (int p = 0; p < 4; ++p) {
      int c = p * 4 + w;
      gll16(Ac + (size_t)(m0 + c * 8 + srow) * (EMB * 2) + k0 * 2 + scol, sA + c * 512);
    }
#pragma unroll
    for (int p = 0; p < 2; ++p) {
      int c = p * 4 + w;
      size_t rowB = (size_t)(n0 + c * 8 + srow) * (EMB * 2) + k0 * 2 + scol;
#pragma unroll
      for (int mat = 0; mat < 3; ++mat)
        gll16(Wc[mat] + rowB, &sW[mat][c * 512]);
    }
    __syncthreads();   // drains vmcnt: staged tiles visible
#pragma unroll
    for (int ks = 0; ks < 2; ++ks) {
      bf16x8 af[2];
#pragma unroll
      for (int i = 0; i < 2; ++i)
        af[i] = *reinterpret_cast<const bf16x8*>(&sA[offA[i][ks]]);
#pragma unroll
      for (int mat = 0; mat < 3; ++mat) {
        bf16x8 bf[4];
#pragma unroll
        for (int i = 0; i < 4; ++i)
          bf[i] = *reinterpret_cast<const bf16x8*>(&sW[mat][offB[i][ks]]);
#pragma unroll
        for (int mi = 0; mi < 2; ++mi)
#pragma unroll
          for (int ni = 0; ni < 4; ++ni)
            acc[mat][mi][ni] = MFMA16(af[mi], bf[ni], acc[mat][mi][ni]);
      }
    }
    __syncthreads();   // tiles consumed; safe to restage
  }

  // ---- epilogue ----  (C/D: row=(lane>>4)*4+reg, col=lane&15)
  const int hh = n0 >> 6;                              // one head per block
#pragma unroll
  for (int mi = 0; mi < 2; ++mi)
#pragma unroll
    for (int ni = 0; ni < 4; ++ni) {
      int cg = n0 + ni * 16 + l15;
      int d = cg & (DH - 1);
#pragma unroll
      for (int j = 0; j < 4; ++j) {
        int rg = m0 + w * 32 + mi * 16 + g * 4 + j;
        int bb = rg >> 11, r = rg & (NSEQ - 1);
        size_t hb = (size_t)(bb * NH + hh);
        size_t idx = (hb * NSEQ + r) * DH + d;
        Qw[idx] = f2bf((acc[0][mi][ni][j] + bq[cg]) * QSCALE);
        Kw[idx] = f2bf(acc[1][mi][ni][j] + bk[cg]);
      }
      float bvc = bv[cg];
      int rg0 = m0 + w * 32 + mi * 16 + g * 4;
      bf16x4 pv = {f2bf(acc[2][mi][ni][0] + bvc), f2bf(acc[2][mi][ni][1] + bvc),
                   f2bf(acc[2][mi][ni][2] + bvc), f2bf(acc[2][mi][ni][3] + bvc)};
      *reinterpret_cast<bf16x4*>(Vtw + (size_t)cg * BSEQ + rg0) = pv;
    }
}

// ================= output projection (r13 proven: 128x128, 512 blocks = 2/CU) =================
__device__ __forceinline__ void gemm_loop(__bf16* sA, __bf16* sB,
                                          const __bf16* __restrict__ A,
                                          const __bf16* __restrict__ W,
                                          int m0, int n0, f32x4 (&acc)[4][4]) {
  const int t = threadIdx.x;
  const int lane = t & 63, w = t >> 6;
  const int wr = w >> 1, wc = w & 1;
  const int l15 = lane & 15, g = lane >> 4;
  const char* Ac = (const char*)A;
  const char* Wc = (const char*)W;
  const int srow = lane >> 3;
  const int scol = ((lane & 7) ^ srow) * 16;

  int offA[4][2], offB[4][2];
#pragma unroll
  for (int i = 0; i < 4; ++i)
#pragma unroll
    for (int ks = 0; ks < 2; ++ks) {
      int ra = wr * 64 + i * 16 + l15;
      int rb = wc * 64 + i * 16 + l15;
      offA[i][ks] = (ra * 128 + ((ks * 64 + g * 16) ^ ((l15 & 7) << 4))) >> 1;
      offB[i][ks] = (rb * 128 + ((ks * 64 + g * 16) ^ ((l15 & 7) << 4))) >> 1;
    }

#pragma unroll 1
  for (int k0 = 0; k0 < EMB; k0 += 64) {
#pragma unroll
    for (int p = 0; p < 4; ++p) {
      int c = p * 4 + w;
      gll16(Ac + (size_t)(m0 + c * 8 + srow) * (EMB * 2) + k0 * 2 + scol, sA + c * 512);
      gll16(Wc + (size_t)(n0 + c * 8 + srow) * (EMB * 2) + k0 * 2 + scol, sB + c * 512);
    }
    __syncthreads();
    bf16x8 af[4][2], bfr[4][2];
#pragma unroll
    for (int i = 0; i < 4; ++i)
#pragma unroll
      for (int ks = 0; ks < 2; ++ks) {
        af[i][ks]  = *reinterpret_cast<const bf16x8*>(sA + offA[i][ks]);
        bfr[i][ks] = *reinterpret_cast<const bf16x8*>(sB + offB[i][ks]);
      }
#pragma unroll
    for (int ks = 0; ks < 2; ++ks)
#pragma unroll
      for (int mi = 0; mi < 4; ++mi)
#pragma unroll
        for (int ni = 0; ni < 4; ++ni)
          acc[mi][ni] = MFMA16(af[mi][ks], bfr[ni][ks], acc[mi][ni]);
    __syncthreads();
  }
}

__global__ __launch_bounds__(256) void oproj_bf(const __bf16* __restrict__ Abf,
                                                const __bf16* __restrict__ W,
                                                const float* __restrict__ bias,
                                                float* __restrict__ outp) {
  __shared__ __align__(16) __bf16 smem[2][128 * 64];
  int flat = blockIdx.x + 8 * blockIdx.y;
  int logical = (flat & 7) * 64 + (flat >> 3);
  const int m0 = (logical >> 3) * 128, n0 = (logical & 7) * 128;

  f32x4 acc[4][4];
#pragma unroll
  for (int i = 0; i < 4; ++i)
#pragma unroll
    for (int j = 0; j < 4; ++j) acc[i][j] = f32x4{0.f, 0.f, 0.f, 0.f};

  gemm_loop(smem[0], smem[1], Abf, W, m0, n0, acc);

  const int lane = threadIdx.x & 63, w = threadIdx.x >> 6;
  const int wr = w >> 1, wc = w & 1, l15 = lane & 15, g = lane >> 4;
#pragma unroll
  for (int mi = 0; mi < 4; ++mi)
#pragma unroll
    for (int ni = 0; ni < 4; ++ni)
#pragma unroll
      for (int j = 0; j < 4; ++j) {
        int rg = m0 + wr * 64 + mi * 16 + g * 4 + j;
        int cg = n0 + wc * 64 + ni * 16 + l15;
        outp[(size_t)rg * EMB + cg] = acc[mi][ni][j] + bias[cg];
      }
}

// ================= Flash attention (r13 structure; exp2 via raw v_exp_f32) =================
// Only change vs r16: __builtin_amdgcn_exp2f replaces __builtin_exp2f.
// Inputs are bounded (prescaled logits ~ +-12): no denormal/overflow region,
// so the IEEE fixup sequence the generic builtin lowers to is pure waste.
__global__ __launch_bounds__(512) void flash_kernel(const __bf16* __restrict__ Qb,
                                                    const __bf16* __restrict__ Kb,
                                                    const __bf16* __restrict__ Vtb,
                                                    float* __restrict__ attnw,
                                                    __bf16* __restrict__ attnw_bf) {
  __shared__ __align__(16) __bf16 lds[2][16384];  // [buf][ K:8192 | V:8192 ] elements
  const int t = threadIdx.x;
  const int lane = t & 63, w = t >> 6;            // w in [0,8)
  const int l31 = lane & 31, hi = lane >> 5;

  int flat = blockIdx.x + 8 * (blockIdx.y + NH * blockIdx.z);
  int logical = (flat & 7) * 64 + (flat >> 3);
  const int qt = logical & 7, h = (logical >> 3) & 15, b = logical >> 7;

  const size_t hoff = ((size_t)(b * NH + h)) * HSTRIDE;
  const __bf16* Qh = Qb + hoff;                  // [2048][64]
  const char* Kc = (const char*)(Kb + hoff);     // [2048][64]  row = 128 B
  const char* Vc = (const char*)(Vtb + (size_t)(h * DH) * BSEQ + (size_t)b * NSEQ);
  const int q0 = qt * 256 + w * 32;              // this wave's 32 q-rows

  bf16x8 qf[4];
#pragma unroll
  for (int ds = 0; ds < 4; ++ds)
    qf[ds] = *reinterpret_cast<const bf16x8*>(Qh + (size_t)(q0 + l31) * DH + ds * 16 + hi * 8);

  int koff[2][4], voff[4][2];
#pragma unroll
  for (int kt32 = 0; kt32 < 2; ++kt32)
#pragma unroll
    for (int ds = 0; ds < 4; ++ds)
      koff[kt32][ds] = swz((kt32 * 32 + l31) * 128 + ds * 32 + hi * 16) >> 1;
#pragma unroll
  for (int c = 0; c < 4; ++c)
#pragma unroll
    for (int db = 0; db < 2; ++db)
      voff[c][db] = swz((db * 32 + l31) * 128 + c * 32 + hi * 16) >> 1;

  // stage a 128-kv tile (K 16KB + V 16KB); V row stride = BSEQ*2 = 16KB
  auto stage = [&](int bf, int kt) {
#pragma unroll
    for (int hh = 0; hh < 2; ++hh) {
      int L = w * 1024 + lane * 16;
      int s = swz(L);
      gll16(Kc + (size_t)(kt + hh * 64) * 128 + s, &lds[bf][hh * 4096 + w * 512]);
      int d = s >> 7, rem = s & 127;
      gll16(Vc + (size_t)d * (BSEQ * 2) + (kt + hh * 64) * 2 + rem,
            &lds[bf][8192 + hh * 4096 + w * 512]);
    }
  };

  f32x16 o0{}, o1{}, osum{};
  const f32x16 kZero{};                 // hoisted zero C operand
  bf16x8 vones;
#pragma unroll
  for (int i = 0; i < 8; ++i) vones[i] = (__bf16)1.0f;

  stage(0, 0);
  __syncthreads();

#pragma unroll 1
  for (int it = 0; it < NSEQ / 128; ++it) {
    const int cur = it & 1;
    if (it + 1 < NSEQ / 128) stage(cur ^ 1, (it + 1) * 128);

#pragma unroll
    for (int sub = 0; sub < 2; ++sub) {
      const __bf16* Kl = lds[cur] + sub * 4096;
      const __bf16* Vl = lds[cur] + 8192 + sub * 4096;

      bf16x8 kf[2][4];
#pragma unroll
      for (int kt32 = 0; kt32 < 2; ++kt32)
#pragma unroll
        for (int ds = 0; ds < 4; ++ds)
          kf[kt32][ds] = *reinterpret_cast<const bf16x8*>(Kl + koff[kt32][ds]);

      f32x16 s0, s1;
      __builtin_amdgcn_s_setprio(1);
      s0 = MFMA32(kf[0][0], qf[0], kZero);
      s1 = MFMA32(kf[1][0], qf[0], kZero);
#pragma unroll
      for (int ds = 1; ds < 4; ++ds) s0 = MFMA32(kf[0][ds], qf[ds], s0);
#pragma unroll
      for (int ds = 1; ds < 4; ++ds) s1 = MFMA32(kf[1][ds], qf[ds], s1);
      __builtin_amdgcn_s_setprio(0);

      bf16x8 vf[4][2];
#pragma unroll
      for (int c = 0; c < 4; ++c)
#pragma unroll
        for (int db = 0; db < 2; ++db)
          vf[c][db] = *reinterpret_cast<const bf16x8*>(Vl + voff[c][db]);

      // softmax: p = exp2(S) via raw v_exp_f32 (no IEEE denormal fixup)
#pragma unroll
      for (int r = 0; r < 16; ++r) s0[r] = __builtin_amdgcn_exp2f(s0[r]);
#pragma unroll
      for (int r = 0; r < 16; ++r) s1[r] = __builtin_amdgcn_exp2f(s1[r]);

      u32 pk0[8], pk1[8];
#pragma unroll
      for (int j = 0; j < 8; ++j) pk0[j] = pkbf(s0[2 * j], s0[2 * j + 1]);
#pragma unroll
      for (int j = 0; j < 8; ++j) pk1[j] = pkbf(s1[2 * j], s1[2 * j + 1]);

      auto pv_step = [&](u32& a0, u32& a1, u32& a2, u32& a3, int c) {
        asm("v_permlane32_swap_b32 %0, %1" : "+v"(a0), "+v"(a2));
        asm("v_permlane32_swap_b32 %0, %1" : "+v"(a1), "+v"(a3));
        u32x4 wv = {a0, a1, a2, a3};
        bf16x8 pa = __builtin_bit_cast(bf16x8, wv);
        o0 = MFMA32(pa, vf[c][0], o0);
        o1 = MFMA32(pa, vf[c][1], o1);
        osum = MFMA32(pa, vones, osum);
      };
      __builtin_amdgcn_s_setprio(1);
      pv_step(pk0[0], pk0[1], pk0[2], pk0[3], 0);
      pv_step(pk0[4], pk0[5], pk0[6], pk0[7], 1);
      pv_step(pk1[0], pk1[1], pk1[2], pk1[3], 2);
      pv_step(pk1[4], pk1[5], pk1[6], pk1[7], 3);
      __builtin_amdgcn_s_setprio(0);
    }

    __syncthreads();   // drains staging vmcnt + lgkm; safe buffer flip
  }

#pragma unroll
  for (int r = 0; r < 16; ++r) {
    int qq = (r & 3) + 8 * (r >> 2) + 4 * hi;
    float invq = 1.0f / osum[r];
    int row = q0 + qq;
    float v0 = o0[r] * invq, v1 = o1[r] * invq;
    float* base = attnw + ((size_t)(b * NSEQ + row)) * EMB + h * DH;
    base[l31]      = v0;
    base[32 + l31] = v1;
    __bf16* bb2 = attnw_bf + ((size_t)(b * NSEQ + row)) * EMB + h * DH;
    bb2[l31]      = f2bf(v0);
    bb2[32 + l31] = f2bf(v1);
  }
}

extern "C" void kernel_launch(void* const* d_in, const int* in_sizes, int n_in,
                              void* d_out, int out_size, void* d_ws, size_t ws_size,
                              hipStream_t stream) {
  const float* q  = (const float*)d_in[0];
  const float* Wq = (const float*)d_in[1];
  const float* bq = (const float*)d_in[2];
  const float* Wk = (const float*)d_in[3];
  const float* bk = (const float*)d_in[4];
  const float* Wv = (const float*)d_in[5];
  const float* bv = (const float*)d_in[6];
  const float* Wo = (const float*)d_in[7];
  const float* bo = (const float*)d_in[8];

  float* outp  = (float*)d_out;
  float* attnw = outp + MAT;            // second tuple element

  // ws = Q | K | Vt | Xbf(->attnw_bf) | Wbf[4]   (bf16; ~75.5 MB, fits: r7)
  __bf16* Qw   = (__bf16*)d_ws;
  __bf16* Kw   = Qw + MAT;
  __bf16* Vtw  = Qw + 2 * MAT;          // layout [EMB][BSEQ]
  __bf16* Xbf  = Qw + 3 * MAT;          // aliased as attnw_bf after qkv
  __bf16* Wbf  = Qw + 4 * MAT;

  const int xblocks = (int)(MAT / 4 / 256);
  const int wblocks = (int)(4 * WSZ / 4 / 256);
  cvt_all<<<xblocks + wblocks, 256, 0, stream>>>(q, Wq, Wk, Wv, Wo, Xbf, Wbf);

  qkv3<<<dim3(16, 64), 256, 0, stream>>>(Xbf, Wbf, bq, bk, bv, Qw, Kw, Vtw);

  flash_kernel<<<dim3(8, NH, NB), 512, 0, stream>>>(Qw, Kw, Vtw, attnw, Xbf);

  oproj_bf<<<dim3(8, 64), 256, 0, stream>>>(Xbf, Wbf + 3 * WSZ, bo, outp);
}

// Round 18
// 183.848 us; speedup vs baseline: 1.2820x; 1.0245x over previous
//
#include <hip/hip_runtime.h>

typedef float  f32x4  __attribute__((ext_vector_type(4)));
typedef float  f32x16 __attribute__((ext_vector_type(16)));
typedef __bf16 bf16x2 __attribute__((ext_vector_type(2)));
typedef __bf16 bf16x4 __attribute__((ext_vector_type(4)));
typedef __bf16 bf16x8 __attribute__((ext_vector_type(8)));
typedef unsigned int u32;
typedef u32 u32x4 __attribute__((ext_vector_type(4)));

#define MFMA16(a, b, c) __builtin_amdgcn_mfma_f32_16x16x32_bf16((a), (b), (c), 0, 0, 0)
#define MFMA32(a, b, c) __builtin_amdgcn_mfma_f32_32x32x16_bf16((a), (b), (c), 0, 0, 0)

constexpr int EMB  = 1024;
constexpr int NSEQ = 2048;
constexpr int NB   = 4;
constexpr int NH   = 16;
constexpr int DH   = 64;
constexpr size_t HSTRIDE = (size_t)NSEQ * DH;        // elements per head (Q/K)
constexpr size_t MAT     = (size_t)NB * NSEQ * EMB;  // 8388608
constexpr size_t WSZ     = (size_t)EMB * EMB;        // 1048576
constexpr int    BSEQ    = NB * NSEQ;                // 8192 (V^T row length)
constexpr float  QSCALE  = 0.18033688011112042f;     // 0.125 * log2(e)

__device__ __forceinline__ __bf16 f2bf(float f) { return (__bf16)f; }

__device__ __forceinline__ u32 pkbf(float a, float b) {
  bf16x2 t = {(__bf16)a, (__bf16)b};
  return __builtin_bit_cast(u32, t);
}

// XOR swizzle (involution) for 128B-row tiles: rows (bits 7-9) into 16B-slot bits (4-6).
__device__ __forceinline__ int swz(int a) { return a ^ (((a >> 7) & 7) << 4); }

// async global->LDS, 16B per lane; LDS dest = wave-uniform base + lane*16.
__device__ __forceinline__ void gll16(const void* g, void* l) {
  __builtin_amdgcn_global_load_lds((const __attribute__((address_space(1))) unsigned*)g,
                                   (__attribute__((address_space(3))) unsigned*)l, 16, 0, 0);
}

// ================= conversion pre-pass (single launch) =================
__global__ __launch_bounds__(256) void cvt_all(const float* __restrict__ x,
                                               const float* __restrict__ w0,
                                               const float* __restrict__ w1,
                                               const float* __restrict__ w2,
                                               const float* __restrict__ w3,
                                               __bf16* __restrict__ Xbf,
                                               __bf16* __restrict__ Wbf) {
  const int xblocks = (int)(MAT / 4 / 256);
  const int wslice  = (int)(WSZ / 4 / 256);
  const float* src;
  __bf16* dst;
  size_t idx;
  if (blockIdx.x < (unsigned)xblocks) {
    src = x; dst = Xbf;
    idx = (size_t)blockIdx.x * 256 + threadIdx.x;
  } else {
    int j = blockIdx.x - xblocks;
    int z = j / wslice, r = j % wslice;
    const float* srcs[4] = {w0, w1, w2, w3};
    src = srcs[z];
    dst = Wbf + (size_t)z * WSZ;
    idx = (size_t)r * 256 + threadIdx.x;
  }
  f32x4 v = *reinterpret_cast<const f32x4*>(src + idx * 4);
  bf16x4 o = {f2bf(v[0]), f2bf(v[1]), f2bf(v[2]), f2bf(v[3])};
  *reinterpret_cast<bf16x4*>(dst + idx * 4) = o;
}

// ================= fused 3-output QKV GEMM, 128x64 tile (r13 proven) =================
__global__ __launch_bounds__(256) void qkv3(const __bf16* __restrict__ Xbf,
                                            const __bf16* __restrict__ Wbf,
                                            const float* __restrict__ bq,
                                            const float* __restrict__ bk,
                                            const float* __restrict__ bv,
                                            __bf16* __restrict__ Qw,
                                            __bf16* __restrict__ Kw,
                                            __bf16* __restrict__ Vtw) {
  __shared__ __align__(16) __bf16 sA[128 * 64];        // 16KB
  __shared__ __align__(16) __bf16 sW[3][64 * 64];      // 3 x 8KB
  const int t = threadIdx.x;
  const int lane = t & 63, w = t >> 6;
  const int l15 = lane & 15, g = lane >> 4;

  // bijective XCD remap over 1024 blocks
  int flat = blockIdx.x + 16 * blockIdx.y;
  int logical = (flat & 7) * 128 + (flat >> 3);
  const int m0 = (logical >> 4) * 128, n0 = (logical & 15) * 64;

  const char* Ac  = (const char*)Xbf;
  const char* Wc[3] = {(const char*)(Wbf + 0 * WSZ),
                       (const char*)(Wbf + 1 * WSZ),
                       (const char*)(Wbf + 2 * WSZ)};

  const int srow = lane >> 3;                          // 8 rows / chunk
  const int scol = ((lane & 7) ^ srow) * 16;           // pre-swizzled source col byte

  int offA[2][2], offB[4][2];
#pragma unroll
  for (int i = 0; i < 2; ++i)
#pragma unroll
    for (int ks = 0; ks < 2; ++ks) {
      int ra = w * 32 + i * 16 + l15;
      offA[i][ks] = (ra * 128 + ((ks * 64 + g * 16) ^ ((l15 & 7) << 4))) >> 1;
    }
#pragma unroll
  for (int i = 0; i < 4; ++i)
#pragma unroll
    for (int ks = 0; ks < 2; ++ks) {
      int rb = i * 16 + l15;
      offB[i][ks] = (rb * 128 + ((ks * 64 + g * 16) ^ ((l15 & 7) << 4))) >> 1;
    }

  f32x4 acc[3][2][4];
#pragma unroll
  for (int m = 0; m < 3; ++m)
#pragma unroll
    for (int i = 0; i < 2; ++i)
#pragma unroll
      for (int j = 0; j < 4; ++j) acc[m][i][j] = f32x4{0.f, 0.f, 0.f, 0.f};

#pragma unroll 1
  for (int k0 = 0; k0 < EMB; k0 += 64) {
#pragma unroll
    for (int p = 0; p < 4; ++p) {
      int c = p * 4 + w;
      gll16(Ac + (size_t)(m0 + c * 8 + srow) * (EMB * 2) + k0 * 2 + scol, sA + c * 512);
    }
#pragma unroll
    for (int p = 0; p < 2; ++p) {
      int c = p * 4 + w;
      size_t rowB = (size_t)(n0 + c * 8 + srow) * (EMB * 2) + k0 * 2 + scol;
#pragma unroll
      for (int mat = 0; mat < 3; ++mat)
        gll16(Wc[mat] + rowB, &sW[mat][c * 512]);
    }
    __syncthreads();   // drains vmcnt: staged tiles visible
#pragma unroll
    for (int ks = 0; ks < 2; ++ks) {
      bf16x8 af[2];
#pragma unroll
      for (int i = 0; i < 2; ++i)
        af[i] = *reinterpret_cast<const bf16x8*>(&sA[offA[i][ks]]);
#pragma unroll
      for (int mat = 0; mat < 3; ++mat) {
        bf16x8 bf[4];
#pragma unroll
        for (int i = 0; i < 4; ++i)
          bf[i] = *reinterpret_cast<const bf16x8*>(&sW[mat][offB[i][ks]]);
#pragma unroll
        for (int mi = 0; mi < 2; ++mi)
#pragma unroll
          for (int ni = 0; ni < 4; ++ni)
            acc[mat][mi][ni] = MFMA16(af[mi], bf[ni], acc[mat][mi][ni]);
      }
    }
    __syncthreads();   // tiles consumed; safe to restage
  }

  // ---- epilogue ----  (C/D: row=(lane>>4)*4+reg, col=lane&15)
  const int hh = n0 >> 6;                              // one head per block
#pragma unroll
  for (int mi = 0; mi < 2; ++mi)
#pragma unroll
    for (int ni = 0; ni < 4; ++ni) {
      int cg = n0 + ni * 16 + l15;
      int d = cg & (DH - 1);
#pragma unroll
      for (int j = 0; j < 4; ++j) {
        int rg = m0 + w * 32 + mi * 16 + g * 4 + j;
        int bb = rg >> 11, r = rg & (NSEQ - 1);
        size_t hb = (size_t)(bb * NH + hh);
        size_t idx = (hb * NSEQ + r) * DH + d;
        Qw[idx] = f2bf((acc[0][mi][ni][j] + bq[cg]) * QSCALE);
        Kw[idx] = f2bf(acc[1][mi][ni][j] + bk[cg]);
      }
      float bvc = bv[cg];
      int rg0 = m0 + w * 32 + mi * 16 + g * 4;
      bf16x4 pv = {f2bf(acc[2][mi][ni][0] + bvc), f2bf(acc[2][mi][ni][1] + bvc),
                   f2bf(acc[2][mi][ni][2] + bvc), f2bf(acc[2][mi][ni][3] + bvc)};
      *reinterpret_cast<bf16x4*>(Vtw + (size_t)cg * BSEQ + rg0) = pv;
    }
}

// ================= output projection (r13 proven: 128x128, 512 blocks = 2/CU) =================
__device__ __forceinline__ void gemm_loop(__bf16* sA, __bf16* sB,
                                          const __bf16* __restrict__ A,
                                          const __bf16* __restrict__ W,
                                          int m0, int n0, f32x4 (&acc)[4][4]) {
  const int t = threadIdx.x;
  const int lane = t & 63, w = t >> 6;
  const int wr = w >> 1, wc = w & 1;
  const int l15 = lane & 15, g = lane >> 4;
  const char* Ac = (const char*)A;
  const char* Wc = (const char*)W;
  const int srow = lane >> 3;
  const int scol = ((lane & 7) ^ srow) * 16;

  int offA[4][2], offB[4][2];
#pragma unroll
  for (int i = 0; i < 4; ++i)
#pragma unroll
    for (int ks = 0; ks < 2; ++ks) {
      int ra = wr * 64 + i * 16 + l15;
      int rb = wc * 64 + i * 16 + l15;
      offA[i][ks] = (ra * 128 + ((ks * 64 + g * 16) ^ ((l15 & 7) << 4))) >> 1;
      offB[i][ks] = (rb * 128 + ((ks * 64 + g * 16) ^ ((l15 & 7) << 4))) >> 1;
    }

#pragma unroll 1
  for (int k0 = 0; k0 < EMB; k0 += 64) {
#pragma unroll
    for (int p = 0; p < 4; ++p) {
      int c = p * 4 + w;
      gll16(Ac + (size_t)(m0 + c * 8 + srow) * (EMB * 2) + k0 * 2 + scol, sA + c * 512);
      gll16(Wc + (size_t)(n0 + c * 8 + srow) * (EMB * 2) + k0 * 2 + scol, sB + c * 512);
    }
    __syncthreads();
    bf16x8 af[4][2], bfr[4][2];
#pragma unroll
    for (int i = 0; i < 4; ++i)
#pragma unroll
      for (int ks = 0; ks < 2; ++ks) {
        af[i][ks]  = *reinterpret_cast<const bf16x8*>(sA + offA[i][ks]);
        bfr[i][ks] = *reinterpret_cast<const bf16x8*>(sB + offB[i][ks]);
      }
#pragma unroll
    for (int ks = 0; ks < 2; ++ks)
#pragma unroll
      for (int mi = 0; mi < 4; ++mi)
#pragma unroll
        for (int ni = 0; ni < 4; ++ni)
          acc[mi][ni] = MFMA16(af[mi][ks], bfr[ni][ks], acc[mi][ni]);
    __syncthreads();
  }
}

__global__ __launch_bounds__(256) void oproj_bf(const __bf16* __restrict__ Abf,
                                                const __bf16* __restrict__ W,
                                                const float* __restrict__ bias,
                                                float* __restrict__ outp) {
  __shared__ __align__(16) __bf16 smem[2][128 * 64];
  int flat = blockIdx.x + 8 * blockIdx.y;
  int logical = (flat & 7) * 64 + (flat >> 3);
  const int m0 = (logical >> 3) * 128, n0 = (logical & 7) * 128;

  f32x4 acc[4][4];
#pragma unroll
  for (int i = 0; i < 4; ++i)
#pragma unroll
    for (int j = 0; j < 4; ++j) acc[i][j] = f32x4{0.f, 0.f, 0.f, 0.f};

  gemm_loop(smem[0], smem[1], Abf, W, m0, n0, acc);

  const int lane = threadIdx.x & 63, w = threadIdx.x >> 6;
  const int wr = w >> 1, wc = w & 1, l15 = lane & 15, g = lane >> 4;
#pragma unroll
  for (int mi = 0; mi < 4; ++mi)
#pragma unroll
    for (int ni = 0; ni < 4; ++ni)
#pragma unroll
      for (int j = 0; j < 4; ++j) {
        int rg = m0 + wr * 64 + mi * 16 + g * 4 + j;
        int cg = n0 + wc * 64 + ni * 16 + l15;
        outp[(size_t)rg * EMB + cg] = acc[mi][ni][j] + bias[cg];
      }
}

// ================= Flash attention (r17 + denominator back on VALU) =================
// r17 made VALU the slack pipe (36.8 vs MFMA 41.6); the osum MFMA-with-ones
// (r8, added when VALU was 70%) is now 20% of MFMA work on the binding pipe.
// Swap back to r7's per-lane f32 partial sums (lane l31 holds row q=l31's
// partials; one shfl_xor(32) + __shfl broadcast at the end).
__global__ __launch_bounds__(512) void flash_kernel(const __bf16* __restrict__ Qb,
                                                    const __bf16* __restrict__ Kb,
                                                    const __bf16* __restrict__ Vtb,
                                                    float* __restrict__ attnw,
                                                    __bf16* __restrict__ attnw_bf) {
  __shared__ __align__(16) __bf16 lds[2][16384];  // [buf][ K:8192 | V:8192 ] elements
  const int t = threadIdx.x;
  const int lane = t & 63, w = t >> 6;            // w in [0,8)
  const int l31 = lane & 31, hi = lane >> 5;

  int flat = blockIdx.x + 8 * (blockIdx.y + NH * blockIdx.z);
  int logical = (flat & 7) * 64 + (flat >> 3);
  const int qt = logical & 7, h = (logical >> 3) & 15, b = logical >> 7;

  const size_t hoff = ((size_t)(b * NH + h)) * HSTRIDE;
  const __bf16* Qh = Qb + hoff;                  // [2048][64]
  const char* Kc = (const char*)(Kb + hoff);     // [2048][64]  row = 128 B
  const char* Vc = (const char*)(Vtb + (size_t)(h * DH) * BSEQ + (size_t)b * NSEQ);
  const int q0 = qt * 256 + w * 32;              // this wave's 32 q-rows

  bf16x8 qf[4];
#pragma unroll
  for (int ds = 0; ds < 4; ++ds)
    qf[ds] = *reinterpret_cast<const bf16x8*>(Qh + (size_t)(q0 + l31) * DH + ds * 16 + hi * 8);

  int koff[2][4], voff[4][2];
#pragma unroll
  for (int kt32 = 0; kt32 < 2; ++kt32)
#pragma unroll
    for (int ds = 0; ds < 4; ++ds)
      koff[kt32][ds] = swz((kt32 * 32 + l31) * 128 + ds * 32 + hi * 16) >> 1;
#pragma unroll
  for (int c = 0; c < 4; ++c)
#pragma unroll
    for (int db = 0; db < 2; ++db)
      voff[c][db] = swz((db * 32 + l31) * 128 + c * 32 + hi * 16) >> 1;

  // stage a 128-kv tile (K 16KB + V 16KB); V row stride = BSEQ*2 = 16KB
  auto stage = [&](int bf, int kt) {
#pragma unroll
    for (int hh = 0; hh < 2; ++hh) {
      int L = w * 1024 + lane * 16;
      int s = swz(L);
      gll16(Kc + (size_t)(kt + hh * 64) * 128 + s, &lds[bf][hh * 4096 + w * 512]);
      int d = s >> 7, rem = s & 127;
      gll16(Vc + (size_t)d * (BSEQ * 2) + (kt + hh * 64) * 2 + rem,
            &lds[bf][8192 + hh * 4096 + w * 512]);
    }
  };

  f32x16 o0{}, o1{};
  float lsum = 0.f;                     // per-lane partial row sum (row q = l31)
  const f32x16 kZero{};                 // hoisted zero C operand

  stage(0, 0);
  __syncthreads();

#pragma unroll 1
  for (int it = 0; it < NSEQ / 128; ++it) {
    const int cur = it & 1;
    if (it + 1 < NSEQ / 128) stage(cur ^ 1, (it + 1) * 128);

#pragma unroll
    for (int sub = 0; sub < 2; ++sub) {
      const __bf16* Kl = lds[cur] + sub * 4096;
      const __bf16* Vl = lds[cur] + 8192 + sub * 4096;

      bf16x8 kf[2][4];
#pragma unroll
      for (int kt32 = 0; kt32 < 2; ++kt32)
#pragma unroll
        for (int ds = 0; ds < 4; ++ds)
          kf[kt32][ds] = *reinterpret_cast<const bf16x8*>(Kl + koff[kt32][ds]);

      f32x16 s0, s1;
      __builtin_amdgcn_s_setprio(1);
      s0 = MFMA32(kf[0][0], qf[0], kZero);
      s1 = MFMA32(kf[1][0], qf[0], kZero);
#pragma unroll
      for (int ds = 1; ds < 4; ++ds) s0 = MFMA32(kf[0][ds], qf[ds], s0);
#pragma unroll
      for (int ds = 1; ds < 4; ++ds) s1 = MFMA32(kf[1][ds], qf[ds], s1);
      __builtin_amdgcn_s_setprio(0);

      bf16x8 vf[4][2];
#pragma unroll
      for (int c = 0; c < 4; ++c)
#pragma unroll
        for (int db = 0; db < 2; ++db)
          vf[c][db] = *reinterpret_cast<const bf16x8*>(Vl + voff[c][db]);

      // softmax: p = exp2(S) via raw v_exp_f32 (no IEEE denormal fixup)
#pragma unroll
      for (int r = 0; r < 16; ++r) s0[r] = __builtin_amdgcn_exp2f(s0[r]);
#pragma unroll
      for (int r = 0; r < 16; ++r) s1[r] = __builtin_amdgcn_exp2f(s1[r]);

      // denominator on the VALU (slack pipe): tree-sum 32 values
      {
        float t0 = ((s0[0] + s0[1]) + (s0[2] + s0[3])) + ((s0[4] + s0[5]) + (s0[6] + s0[7]));
        float t1 = ((s0[8] + s0[9]) + (s0[10] + s0[11])) + ((s0[12] + s0[13]) + (s0[14] + s0[15]));
        float t2 = ((s1[0] + s1[1]) + (s1[2] + s1[3])) + ((s1[4] + s1[5]) + (s1[6] + s1[7]));
        float t3 = ((s1[8] + s1[9]) + (s1[10] + s1[11])) + ((s1[12] + s1[13]) + (s1[14] + s1[15]));
        lsum += (t0 + t1) + (t2 + t3);
      }

      u32 pk0[8], pk1[8];
#pragma unroll
      for (int j = 0; j < 8; ++j) pk0[j] = pkbf(s0[2 * j], s0[2 * j + 1]);
#pragma unroll
      for (int j = 0; j < 8; ++j) pk1[j] = pkbf(s1[2 * j], s1[2 * j + 1]);

      auto pv_step = [&](u32& a0, u32& a1, u32& a2, u32& a3, int c) {
        asm("v_permlane32_swap_b32 %0, %1" : "+v"(a0), "+v"(a2));
        asm("v_permlane32_swap_b32 %0, %1" : "+v"(a1), "+v"(a3));
        u32x4 wv = {a0, a1, a2, a3};
        bf16x8 pa = __builtin_bit_cast(bf16x8, wv);
        o0 = MFMA32(pa, vf[c][0], o0);
        o1 = MFMA32(pa, vf[c][1], o1);
      };
      __builtin_amdgcn_s_setprio(1);
      pv_step(pk0[0], pk0[1], pk0[2], pk0[3], 0);
      pv_step(pk0[4], pk0[5], pk0[6], pk0[7], 1);
      pv_step(pk1[0], pk1[1], pk1[2], pk1[3], 2);
      pv_step(pk1[4], pk1[5], pk1[6], pk1[7], 3);
      __builtin_amdgcn_s_setprio(0);
    }

    __syncthreads();   // drains staging vmcnt + lgkm; safe buffer flip
  }

  // row total: lane covers half the k's of row q=l31; partner has the rest
  lsum += __shfl_xor(lsum, 32);
  float inv = 1.0f / lsum;

#pragma unroll
  for (int r = 0; r < 16; ++r) {
    int qq = (r & 3) + 8 * (r >> 2) + 4 * hi;
    float invq = __shfl(inv, qq);        // lane qq holds row qq's inv
    int row = q0 + qq;
    float v0 = o0[r] * invq, v1 = o1[r] * invq;
    float* base = attnw + ((size_t)(b * NSEQ + row)) * EMB + h * DH;
    base[l31]      = v0;
    base[32 + l31] = v1;
    __bf16* bb2 = attnw_bf + ((size_t)(b * NSEQ + row)) * EMB + h * DH;
    bb2[l31]      = f2bf(v0);
    bb2[32 + l31] = f2bf(v1);
  }
}

extern "C" void kernel_launch(void* const* d_in, const int* in_sizes, int n_in,
                              void* d_out, int out_size, void* d_ws, size_t ws_size,
                              hipStream_t stream) {
  const float* q  = (const float*)d_in[0];
  const float* Wq = (const float*)d_in[1];
  const float* bq = (const float*)d_in[2];
  const float* Wk = (const float*)d_in[3];
  const float* bk = (const float*)d_in[4];
  const float* Wv = (const float*)d_in[5];
  const float* bv = (const float*)d_in[6];
  const float* Wo = (const float*)d_in[7];
  const float* bo = (const float*)d_in[8];

  float* outp  = (float*)d_out;
  float* attnw = outp + MAT;            // second tuple element

  // ws = Q | K | Vt | Xbf(->attnw_bf) | Wbf[4]   (bf16; ~75.5 MB, fits: r7)
  __bf16* Qw   = (__bf16*)d_ws;
  __bf16* Kw   = Qw + MAT;
  __bf16* Vtw  = Qw + 2 * MAT;          // layout [EMB][BSEQ]
  __bf16* Xbf  = Qw + 3 * MAT;          // aliased as attnw_bf after qkv
  __bf16* Wbf  = Qw + 4 * MAT;

  const int xblocks = (int)(MAT / 4 / 256);
  const int wblocks = (int)(4 * WSZ / 4 / 256);
  cvt_all<<<xblocks + wblocks, 256, 0, stream>>>(q, Wq, Wk, Wv, Wo, Xbf, Wbf);

  qkv3<<<dim3(16, 64), 256, 0, stream>>>(Xbf, Wbf, bq, bk, bv, Qw, Kw, Vtw);

  flash_kernel<<<dim3(8, NH, NB), 512, 0, stream>>>(Qw, Kw, Vtw, attnw, Xbf);

  oproj_bf<<<dim3(8, 64), 256, 0, stream>>>(Xbf, Wbf + 3 * WSZ, bo, outp);
}